// Round 2
// baseline (30907.742 us; speedup 1.0000x reference)
//
#include <hip/hip_runtime.h>
#include <hip/hip_bf16.h>

// LSTM B=64 L=512 H=1024 x2, persistent kernel v2.
// v2 changes vs v1:
//  - NO per-step release/acquire fences (v1's wbl2+buffer_inv per step was both
//    the 21ms cost and, missing on the layer-1 x-read path, the replay-divergence bug)
//  - all cross-block step data goes through the LLC coherence point:
//    writes = relaxed agent atomic stores (write-through), h reads = relaxed agent
//    atomic loads (cache-bypass). One buffer_inv per block at layer-1 entry.
//  - 64 blocks x 512 threads (block owns 16 h-dims): halves per-step broadcast.

#define B64  64
#define SEQ  512
#define HID  1024
#define KTOT 2048
#define NG   4096
#define NBLK 64
#define DPB  16

typedef __attribute__((ext_vector_type(8)))  short short8;
typedef __attribute__((ext_vector_type(16))) float f32x16;

__device__ inline short bfo(float v){
  __hip_bfloat16 h = __float2bfloat16(v);
  short s; __builtin_memcpy(&s, &h, 2); return s;
}
__device__ inline unsigned packbf2(float a, float b){
  return (unsigned)(unsigned short)bfo(a) | ((unsigned)(unsigned short)bfo(b) << 16);
}
__device__ inline short8 cvt8(float4 a, float4 b){
  short8 r;
  r[0]=bfo(a.x); r[1]=bfo(a.y); r[2]=bfo(a.z); r[3]=bfo(a.w);
  r[4]=bfo(b.x); r[5]=bfo(b.y); r[6]=bfo(b.z); r[7]=bfo(b.w);
  return r;
}
__device__ inline float sigf(float v){ return 1.f/(1.f + __expf(-v)); }
__device__ inline float tanhf2(float v){
  float a = fabsf(v);
  float e = __expf(-2.f*a);
  float r = (1.f-e)/(1.f+e);
  return v < 0.f ? -r : r;
}
__device__ inline f32x16 MFMA(short8 a, short8 b, f32x16 c){
  return __builtin_amdgcn_mfma_f32_32x32x16_bf16(a, b, c, 0, 0, 0);
}

// cache-bypass (LLC-coherent) helpers
__device__ inline short8 ldh8(const short* p){
  unsigned long long a = __hip_atomic_load((const unsigned long long*)p,
                          __ATOMIC_RELAXED, __HIP_MEMORY_SCOPE_AGENT);
  unsigned long long b = __hip_atomic_load((const unsigned long long*)(p+4),
                          __ATOMIC_RELAXED, __HIP_MEMORY_SCOPE_AGENT);
  short8 r;
  __builtin_memcpy(&r, &a, 8);
  __builtin_memcpy(((char*)&r)+8, &b, 8);
  return r;
}
__device__ inline void st8f(float* p, float a, float b){
  unsigned long long lo, hi; unsigned ua, ub;
  __builtin_memcpy(&ua, &a, 4); __builtin_memcpy(&ub, &b, 4);
  lo = ua; hi = ub; lo |= (hi << 32);
  __hip_atomic_store((unsigned long long*)p, lo, __ATOMIC_RELAXED, __HIP_MEMORY_SCOPE_AGENT);
}
__device__ inline void stu(short* p, unsigned v){
  __hip_atomic_store((unsigned*)p, v, __ATOMIC_RELAXED, __HIP_MEMORY_SCOPE_AGENT);
}

__device__ inline void waitflags(const unsigned* flags, unsigned e, int lane){
  const unsigned* p = flags + lane;
  for(;;){
    unsigned a = __hip_atomic_load(p, __ATOMIC_RELAXED, __HIP_MEMORY_SCOPE_AGENT);
    if (__all(a >= e)) break;
    __builtin_amdgcn_s_sleep(2);
  }
  asm volatile("" ::: "memory");   // keep later loads from being hoisted above the poll
}

// ---------------- prologue kernels ----------------

__global__ void lstm_prep(const float* __restrict__ bi, const float* __restrict__ bh,
                          float* __restrict__ bsum, unsigned* __restrict__ flags)
{
  int i = blockIdx.x*256 + threadIdx.x;
  if (i < 128) flags[i] = 0;
  if (i < 2*NG) bsum[i] = bi[i] + bh[i];
}

// W_i / W_h [2][1024][4096] f32 -> wT [2][4096][2048] bf16 (col-major-by-gatecol, k inner)
__global__ void lstm_tr(const float* __restrict__ Wi, const float* __restrict__ Wh,
                        short* __restrict__ wT)
{
  __shared__ float tile[32][33];
  const int z = blockIdx.z, l = z >> 1, s = z & 1;
  const float* W = (s ? Wh : Wi) + (size_t)l*1024*4096;
  const int k0 = blockIdx.y*32, n0 = blockIdx.x*32;
  const int tx = threadIdx.x & 31, ty = threadIdx.x >> 5;
#pragma unroll
  for (int i = 0; i < 32; i += 8)
    tile[ty+i][tx] = W[(size_t)(k0+ty+i)*4096 + n0 + tx];
  __syncthreads();
#pragma unroll
  for (int i = 0; i < 32; i += 8)
    wT[((size_t)l*NG + n0+ty+i)*KTOT + s*1024 + k0 + tx] = bfo(tile[tx][ty+i]);
}

__global__ void lstm_xbf(const float* __restrict__ x, short* __restrict__ xb)
{
  size_t i = ((size_t)blockIdx.x*256 + threadIdx.x)*8;
  float4 a = *(const float4*)(x + i);
  float4 b = *(const float4*)(x + i + 4);
  *(short8*)(xb + i) = cvt8(a, b);
}

// ---------------- main persistent kernel ----------------

__global__ void __launch_bounds__(512, 2)
lstm_main(const float* __restrict__ x,
          const float* __restrict__ h0in,
          const float* __restrict__ c0in,
          float* __restrict__ dout,
          const short* __restrict__ wT,
          const float* __restrict__ bsum,
          short* __restrict__ hbuf,
          unsigned* __restrict__ flags,
          const short* __restrict__ xbf,
          int use_xbf)
{
  const int blk  = blockIdx.x;      // owns h-dims [blk*16, blk*16+16)
  const int tid  = threadIdx.x;
  const int lane = tid & 63;
  const int wave = tid >> 6;        // 8 waves
  const int cg   = wave & 1;        // col-group (8 dims x 4 gates = 32 cols)
  const int kq   = wave >> 1;       // K-quarter of fused K=2048; 0,1 = x, 2,3 = h

  __shared__ float gtile[2][4][64][33];  // [cg][kq][row][col32] gate partials
  __shared__ float cst[64][17];          // c state
  __shared__ float bsm[64];              // b_i+b_h, [gate*16+dim]

  const int prow = tid >> 3;             // pointwise row 0..63
  const int pj0  = (tid & 7) * 2;        // pointwise dim pair
  const int col  = lane & 31;
  const int rsel = lane >> 5;

  for (int l = 0; l < 2; ++l){
    const unsigned base = l ? 513u : 0u;
    if (l){
      waitflags(flags, 513u, lane);                      // all blocks done layer 0
      __builtin_amdgcn_fence(__ATOMIC_ACQUIRE, "agent"); // one-time inv: fresh dout lines
    }
    if (tid < 64) bsm[tid] = bsum[l*NG + (tid>>4)*HID + blk*DPB + (tid&15)];
    {
      size_t o = ((size_t)l*B64 + prow)*HID + blk*DPB + pj0;
      cst[prow][pj0]   = c0in[o];
      cst[prow][pj0+1] = c0in[o+1];
      // h_{-1} -> parity-1 buffer (step 0 reads parity 1)
      stu(hbuf + (size_t)B64*HID + (size_t)prow*HID + blk*DPB + pj0,
          packbf2(h0in[o], h0in[o+1]));
    }
    // persistent B fragments: 32 cols x 512 k = 128 VGPRs
    short8 bfr[32];
    {
      const int gc = (col>>3)*HID + blk*DPB + cg*8 + (col&7);
      const short* wp = wT + (size_t)l*NG*KTOT + (size_t)gc*KTOT + kq*512 + rsel*8;
#pragma unroll
      for (int s = 0; s < 32; ++s)
        bfr[s] = *(const short8*)(wp + s*16);
    }
    __syncthreads();   // drains vmcnt -> init stores are in LLC
    if (tid == 0)
      __hip_atomic_store(&flags[blk], base+1u, __ATOMIC_RELAXED, __HIP_MEMORY_SCOPE_AGENT);

    float hf0 = 0.f, hf1 = 0.f;   // last h (for h_n)
    float pv0 = 0.f, pv1 = 0.f;   // layer-1 delayed output regs

    for (int t = 0; t < SEQ; ++t){
      f32x16 acc0, acc1;
#pragma unroll
      for (int i = 0; i < 16; ++i){ acc0[i] = 0.f; acc1[i] = 0.f; }

      if (kq < 2){
        // ---- x-part: never waits ----
        const int k0 = kq*512 + rsel*8;
        if (l == 0 && use_xbf){
          const short* p = xbf + ((size_t)col*SEQ + t)*HID + k0;
#pragma unroll
          for (int s = 0; s < 32; ++s){
            acc0 = MFMA(*(const short8*)(p + s*16), bfr[s], acc0);
            acc1 = MFMA(*(const short8*)(p + (size_t)32*SEQ*HID + s*16), bfr[s], acc1);
          }
        } else {
          const float* xs = l ? dout : x;
          const float* p  = xs + ((size_t)col*SEQ + t)*HID + k0;
#pragma unroll
          for (int s = 0; s < 32; ++s){
            float4 f0 = *(const float4*)(p + s*16);
            float4 f1 = *(const float4*)(p + s*16 + 4);
            float4 g0 = *(const float4*)(p + (size_t)32*SEQ*HID + s*16);
            float4 g1 = *(const float4*)(p + (size_t)32*SEQ*HID + s*16 + 4);
            acc0 = MFMA(cvt8(f0,f1), bfr[s], acc0);
            acc1 = MFMA(cvt8(g0,g1), bfr[s], acc1);
          }
        }
      } else {
        // ---- h-part: wait for all blocks' h_{t-1}, then LLC-bypass loads ----
        waitflags(flags, base + 1u + (unsigned)t, lane);
        const short* hs = hbuf + (size_t)((t+1)&1)*B64*HID;
        const short* p  = hs + (size_t)col*HID + (kq-2)*512 + rsel*8;
#pragma unroll
        for (int s = 0; s < 32; ++s){
          acc0 = MFMA(ldh8(p + s*16), bfr[s], acc0);
          acc1 = MFMA(ldh8(p + (size_t)32*HID + s*16), bfr[s], acc1);
        }
      }

      // ---- accumulators -> LDS (C/D: col=lane&31, row=(r&3)+8*(r>>2)+4*(lane>>5)) ----
      {
        const int rb = 4*rsel;
#pragma unroll
        for (int r = 0; r < 16; ++r){
          int rr = (r & 3) + 8*(r >> 2) + rb;
          gtile[cg][kq][rr][col]    = acc0[r];
          gtile[cg][kq][rr+32][col] = acc1[r];
        }
      }
      __syncthreads();

      // ---- pointwise ----
      {
        float hn[2];
#pragma unroll
        for (int e = 0; e < 2; ++e){
          const int j = pj0 + e, jc = j & 7, jg = j >> 3;
          float gv[4];
#pragma unroll
          for (int g = 0; g < 4; ++g){
            float s = bsm[g*16 + j];
            s += gtile[jg][0][prow][g*8+jc];
            s += gtile[jg][1][prow][g*8+jc];
            s += gtile[jg][2][prow][g*8+jc];
            s += gtile[jg][3][prow][g*8+jc];
            gv[g] = s;
          }
          float cp = cst[prow][j];
          float cn = sigf(gv[1])*cp + sigf(gv[0])*tanhf2(gv[2]);
          float hv = sigf(gv[3])*tanhf2(cn);
          cst[prow][j] = cn;
          hn[e] = hv;
        }
        hf0 = hn[0]; hf1 = hn[1];
        stu(hbuf + (size_t)(t&1)*B64*HID + (size_t)prow*HID + blk*DPB + pj0,
            packbf2(hn[0], hn[1]));
        if (l == 0){
          st8f(dout + ((size_t)prow*SEQ + t)*HID + blk*DPB + pj0, hn[0], hn[1]);
        } else {
          if (t > 0)
            st8f(dout + ((size_t)prow*SEQ + (t-1))*HID + blk*DPB + pj0, pv0, pv1);
          pv0 = hn[0]; pv1 = hn[1];
        }
      }
      __syncthreads();   // drains vmcnt -> step-t stores in LLC before flag
      if (tid == 0)
        __hip_atomic_store(&flags[blk], base + 2u + (unsigned)t,
                           __ATOMIC_RELAXED, __HIP_MEMORY_SCOPE_AGENT);
    }

    // ---- layer epilogue ----
    if (l == 1)
      st8f(dout + ((size_t)prow*SEQ + (SEQ-1))*HID + blk*DPB + pj0, pv0, pv1);
    {
      const size_t tb = (size_t)B64*SEQ*HID;
      size_t o = ((size_t)l*B64 + prow)*HID + blk*DPB + pj0;
      st8f(dout + tb + o, hf0, hf1);
      st8f(dout + tb + (size_t)2*B64*HID + o, cst[prow][pj0], cst[prow][pj0+1]);
    }
    __syncthreads();
  }
}

// ---------------- host ----------------

extern "C" void kernel_launch(void* const* d_in, const int* in_sizes, int n_in,
                              void* d_out, int out_size, void* d_ws, size_t ws_size,
                              hipStream_t stream)
{
  const float* x  = (const float*)d_in[0];
  const float* Wi = (const float*)d_in[1];
  const float* bi = (const float*)d_in[2];
  const float* Wh = (const float*)d_in[3];
  const float* bh = (const float*)d_in[4];
  const float* h0 = (const float*)d_in[5];
  const float* c0 = (const float*)d_in[6];
  float* out = (float*)d_out;

  char* ws = (char*)d_ws;
  const size_t off_bsum  = 4096;
  const size_t off_wT    = 65536;
  const size_t off_hbuf  = off_wT + (size_t)2*NG*KTOT*2;        // 32MB bf16 W^T
  const size_t off_xbf   = off_hbuf + (size_t)2*B64*HID*2;      // 256KB h parity
  const size_t need_base = off_xbf;
  const size_t need_xbf  = off_xbf + (size_t)B64*SEQ*HID*2;     // +64MB bf16 x
  if (ws_size < need_base) return;
  const int use_xbf = (ws_size >= need_xbf) ? 1 : 0;

  unsigned* flags = (unsigned*)(ws);
  float*    bsum  = (float*)(ws + off_bsum);
  short*    wT    = (short*)(ws + off_wT);
  short*    hbuf  = (short*)(ws + off_hbuf);
  short*    xbf   = (short*)(ws + off_xbf);

  lstm_prep<<<32, 256, 0, stream>>>(bi, bh, bsum, flags);
  lstm_tr<<<dim3(128, 32, 4), 256, 0, stream>>>(Wi, Wh, wT);
  if (use_xbf) lstm_xbf<<<16384, 256, 0, stream>>>(x, xbf);
  lstm_main<<<NBLK, 512, 0, stream>>>(x, h0, c0, out, wT, bsum, hbuf, flags, xbf, use_xbf);
}

// Round 3
// 7157.738 us; speedup vs baseline: 4.3181x; 4.3181x over previous
//
#include <hip/hip_runtime.h>
#include <hip/hip_bf16.h>

// LSTM B=64 L=512 H=1024 x2, persistent kernel v3.
// v3 vs v2:
//  - fragment-layout h buffers ([kg][row][8] bf16): wave A-loads are dense 512B
//    segments (v2's 8B@2KB-stride bypass loads were ~18us/step of scattered LLC)
//  - sequence-indexed h buffers (slot per t, single-role, deterministic values)
//    -> PLAIN cached reads are safe; producers write through (sc1) to LLC; each
//    XCD's L2 shares the broadcast. One acquire fence per block at entry.
//  - layer pipelining: 64 blocks layer0 + 64 blocks layer1 skewed 1 step:
//    sequential depth 1024 -> 513 steps.
//  - 8-way K-split per wave (K=256 x 64 cols, no duplicate A loads); partial
//    reduction via 4 LDS planes: x-waves ds_write pre-barrier, h-waves RMW post.

#define B64  64
#define SEQ  512
#define HID  1024
#define KTOT 2048
#define NG   4096
#define NBLKL 64
#define DPB  16
#define SLOTS 65536   // shorts per hseq slot = 128 kg * 64 rows * 8

typedef __attribute__((ext_vector_type(8)))  short short8;
typedef __attribute__((ext_vector_type(16))) float f32x16;

__device__ inline short bfo(float v){
  __hip_bfloat16 h = __float2bfloat16(v);
  short s; __builtin_memcpy(&s, &h, 2); return s;
}
__device__ inline unsigned packbf2(float a, float b){
  return (unsigned)(unsigned short)bfo(a) | ((unsigned)(unsigned short)bfo(b) << 16);
}
__device__ inline short8 cvt8(float4 a, float4 b){
  short8 r;
  r[0]=bfo(a.x); r[1]=bfo(a.y); r[2]=bfo(a.z); r[3]=bfo(a.w);
  r[4]=bfo(b.x); r[5]=bfo(b.y); r[6]=bfo(b.z); r[7]=bfo(b.w);
  return r;
}
__device__ inline float sigf(float v){ return 1.f/(1.f + __expf(-v)); }
__device__ inline float tanhf2(float v){
  float a = fabsf(v);
  float e = __expf(-2.f*a);
  float r = (1.f-e)/(1.f+e);
  return v < 0.f ? -r : r;
}
__device__ inline f32x16 MFMA(short8 a, short8 b, f32x16 c){
  return __builtin_amdgcn_mfma_f32_32x32x16_bf16(a, b, c, 0, 0, 0);
}

// LLC-bypass helpers (coherent across XCDs)
__device__ inline short8 ldh8(const short* p){
  unsigned long long a = __hip_atomic_load((const unsigned long long*)p,
                          __ATOMIC_RELAXED, __HIP_MEMORY_SCOPE_AGENT);
  unsigned long long b = __hip_atomic_load((const unsigned long long*)(p+4),
                          __ATOMIC_RELAXED, __HIP_MEMORY_SCOPE_AGENT);
  short8 r;
  __builtin_memcpy(&r, &a, 8);
  __builtin_memcpy(((char*)&r)+8, &b, 8);
  return r;
}
__device__ inline void stu(short* p, unsigned v){
  __hip_atomic_store((unsigned*)p, v, __ATOMIC_RELAXED, __HIP_MEMORY_SCOPE_AGENT);
}

__device__ inline void waitflags(const unsigned* flags, unsigned e, int lane){
  const unsigned* p = flags + lane;
  for(;;){
    unsigned a = __hip_atomic_load(p, __ATOMIC_RELAXED, __HIP_MEMORY_SCOPE_AGENT);
    if (__all(a >= e)) break;
    __builtin_amdgcn_s_sleep(1);
  }
  asm volatile("" ::: "memory");
}

// ---------------- prologue kernels ----------------

__global__ void lstm_prep(const float* __restrict__ bi, const float* __restrict__ bh,
                          float* __restrict__ bsum, unsigned* __restrict__ flagpage)
{
  int i = blockIdx.x*256 + threadIdx.x;
  if (i < 1024) flagpage[i] = 0;          // flags0 @0, flags1 @2048B
  if (i < 2*NG) bsum[i] = bi[i] + bh[i];
}

// W_i/W_h [2][1024][4096] f32 -> wT [2][4096][2048] bf16 (gate-col major, k inner)
__global__ void lstm_tr(const float* __restrict__ Wi, const float* __restrict__ Wh,
                        short* __restrict__ wT)
{
  __shared__ float tile[32][33];
  const int z = blockIdx.z, l = z >> 1, s = z & 1;
  const float* W = (s ? Wh : Wi) + (size_t)l*1024*4096;
  const int k0 = blockIdx.y*32, n0 = blockIdx.x*32;
  const int tx = threadIdx.x & 31, ty = threadIdx.x >> 5;
#pragma unroll
  for (int i = 0; i < 32; i += 8)
    tile[ty+i][tx] = W[(size_t)(k0+ty+i)*4096 + n0 + tx];
  __syncthreads();
#pragma unroll
  for (int i = 0; i < 32; i += 8)
    wT[((size_t)l*NG + n0+ty+i)*KTOT + s*1024 + k0 + tx] = bfo(tile[tx][ty+i]);
}

__global__ void lstm_xbf(const float* __restrict__ x, short* __restrict__ xb)
{
  size_t i = ((size_t)blockIdx.x*256 + threadIdx.x)*8;
  float4 a = *(const float4*)(x + i);
  float4 b = *(const float4*)(x + i + 4);
  *(short8*)(xb + i) = cvt8(a, b);
}

// ---------------- main persistent kernel ----------------

__global__ void __launch_bounds__(512, 1)
lstm_main(const float* __restrict__ x,
          const float* __restrict__ h0in,
          const float* __restrict__ c0in,
          float* __restrict__ dout,
          const short* __restrict__ wT,
          const float* __restrict__ bsum,
          short* __restrict__ hseq0,
          short* __restrict__ h1buf,
          unsigned* __restrict__ flags0,
          unsigned* __restrict__ flags1,
          const short* __restrict__ xbf,
          int use_xbf, int use_seq1)
{
  const int blk  = blockIdx.x;     // 128 blocks
  const int l    = blk & 1;        // layer
  const int lblk = blk >> 1;       // 0..63, owns dims [lblk*16, +16)
  const int tid  = threadIdx.x;
  const int lane = tid & 63;
  const int w    = tid >> 6;       // k-eighth: w<4 = x-part, w>=4 = h-part
  const int col  = lane & 31;
  const int rsel = lane >> 5;

  __shared__ float planes[4][64][68];   // partial gates, plane p = waves p & p+4
  __shared__ float cst[64][17];
  __shared__ float bsm[64];

  const int prow = tid >> 3;            // pointwise row
  const int pj0  = (tid & 7) * 2;       // pointwise dim pair

  __builtin_amdgcn_fence(__ATOMIC_ACQUIRE, "agent");  // once: drop stale L2 lines

  unsigned* myflag = (l ? flags1 : flags0) + lblk;

  // ---- init ----
  if (tid < 64) bsm[tid] = bsum[l*NG + (tid>>4)*HID + lblk*DPB + (tid&15)];
  {
    size_t o = ((size_t)l*B64 + prow)*HID + lblk*DPB + pj0;
    cst[prow][pj0]   = c0in[o];
    cst[prow][pj0+1] = c0in[o+1];
    const int kg = lblk*2 + (pj0>>3);
    // h(-1): layer0 -> hseq0 slot 0; layer1 -> hseq1 slot 0 (or parity 1)
    short* hm1 = l ? (h1buf + (use_seq1 ? (size_t)0 : (size_t)SLOTS)) : hseq0;
    stu(hm1 + ((size_t)kg*64 + prow)*8 + (pj0&7), packbf2(h0in[o], h0in[o+1]));
  }
  // persistent B fragments: 64 cols x 256 k = 128 VGPRs
  short8 bf[2][16];
  {
    const short* wl = wT + (size_t)l*NG*KTOT;
#pragma unroll
    for (int cI = 0; cI < 2; ++cI){
      const int c  = cI*32 + col;
      const int gc = (c>>4)*HID + lblk*DPB + (c&15);
      const short* wp = wl + (size_t)gc*KTOT + w*256 + rsel*8;
#pragma unroll
      for (int s = 0; s < 16; ++s)
        bf[cI][s] = *(const short8*)(wp + s*16);
    }
  }
  __syncthreads();   // drains vmcnt: init write-through stores are in LLC
  if (tid == 0)
    __hip_atomic_store(myflag, 1u, __ATOMIC_RELAXED, __HIP_MEMORY_SCOPE_AGENT);

  float hf0 = 0.f, hf1 = 0.f;

  for (int t = 0; t < SEQ; ++t){
    f32x16 acc[2][2];
#pragma unroll
    for (int a = 0; a < 2; ++a)
#pragma unroll
      for (int b = 0; b < 2; ++b)
#pragma unroll
        for (int i = 0; i < 16; ++i) acc[a][b][i] = 0.f;

    if (w < 4){
      if (l == 0){
        if (use_xbf){
          const short* p0 = xbf + ((size_t)col*SEQ + t)*HID + w*256 + rsel*8;
          const short* p1 = p0 + (size_t)32*SEQ*HID;
#pragma unroll
          for (int s = 0; s < 16; ++s){
            short8 a0 = *(const short8*)(p0 + s*16);
            short8 a1 = *(const short8*)(p1 + s*16);
            acc[0][0] = MFMA(a0, bf[0][s], acc[0][0]);
            acc[0][1] = MFMA(a1, bf[0][s], acc[0][1]);
            acc[1][0] = MFMA(a0, bf[1][s], acc[1][0]);
            acc[1][1] = MFMA(a1, bf[1][s], acc[1][1]);
          }
        } else {
          const float* p0 = x + ((size_t)col*SEQ + t)*HID + w*256 + rsel*8;
          const float* p1 = p0 + (size_t)32*SEQ*HID;
#pragma unroll
          for (int s = 0; s < 16; ++s){
            short8 a0 = cvt8(*(const float4*)(p0 + s*16), *(const float4*)(p0 + s*16 + 4));
            short8 a1 = cvt8(*(const float4*)(p1 + s*16), *(const float4*)(p1 + s*16 + 4));
            acc[0][0] = MFMA(a0, bf[0][s], acc[0][0]);
            acc[0][1] = MFMA(a1, bf[0][s], acc[0][1]);
            acc[1][0] = MFMA(a0, bf[1][s], acc[1][0]);
            acc[1][1] = MFMA(a1, bf[1][s], acc[1][1]);
          }
        }
      } else {
        // layer1 "x" = h0(t) from hseq0 slot t+1 (plain cached, frag layout)
        waitflags(flags0, (unsigned)t + 2u, lane);
        const short* hs = hseq0 + (size_t)(t+1)*SLOTS;
#pragma unroll
        for (int s = 0; s < 16; ++s){
          const int kg = w*32 + s*2 + rsel;
          short8 a0 = *(const short8*)(hs + ((size_t)kg*64 + col)*8);
          short8 a1 = *(const short8*)(hs + ((size_t)kg*64 + 32 + col)*8);
          acc[0][0] = MFMA(a0, bf[0][s], acc[0][0]);
          acc[0][1] = MFMA(a1, bf[0][s], acc[0][1]);
          acc[1][0] = MFMA(a0, bf[1][s], acc[1][0]);
          acc[1][1] = MFMA(a1, bf[1][s], acc[1][1]);
        }
      }
    } else {
      // h-part: own layer's h(t-1)
      if (l == 0){
        waitflags(flags0, (unsigned)t + 1u, lane);
        const short* hs = hseq0 + (size_t)t*SLOTS;
#pragma unroll
        for (int s = 0; s < 16; ++s){
          const int kg = (w-4)*32 + s*2 + rsel;
          short8 a0 = *(const short8*)(hs + ((size_t)kg*64 + col)*8);
          short8 a1 = *(const short8*)(hs + ((size_t)kg*64 + 32 + col)*8);
          acc[0][0] = MFMA(a0, bf[0][s], acc[0][0]);
          acc[0][1] = MFMA(a1, bf[0][s], acc[0][1]);
          acc[1][0] = MFMA(a0, bf[1][s], acc[1][0]);
          acc[1][1] = MFMA(a1, bf[1][s], acc[1][1]);
        }
      } else {
        waitflags(flags1, (unsigned)t + 1u, lane);
        if (use_seq1){
          const short* hs = h1buf + (size_t)t*SLOTS;
#pragma unroll
          for (int s = 0; s < 16; ++s){
            const int kg = (w-4)*32 + s*2 + rsel;
            short8 a0 = *(const short8*)(hs + ((size_t)kg*64 + col)*8);
            short8 a1 = *(const short8*)(hs + ((size_t)kg*64 + 32 + col)*8);
            acc[0][0] = MFMA(a0, bf[0][s], acc[0][0]);
            acc[0][1] = MFMA(a1, bf[0][s], acc[0][1]);
            acc[1][0] = MFMA(a0, bf[1][s], acc[1][0]);
            acc[1][1] = MFMA(a1, bf[1][s], acc[1][1]);
          }
        } else {
          const short* hs = h1buf + (size_t)((t+1)&1)*SLOTS;   // parity fallback
#pragma unroll
          for (int s = 0; s < 16; ++s){
            const int kg = (w-4)*32 + s*2 + rsel;
            short8 a0 = ldh8(hs + ((size_t)kg*64 + col)*8);
            short8 a1 = ldh8(hs + ((size_t)kg*64 + 32 + col)*8);
            acc[0][0] = MFMA(a0, bf[0][s], acc[0][0]);
            acc[0][1] = MFMA(a1, bf[0][s], acc[0][1]);
            acc[1][0] = MFMA(a0, bf[1][s], acc[1][0]);
            acc[1][1] = MFMA(a1, bf[1][s], acc[1][1]);
          }
        }
      }
    }

    // ---- reduction: x-waves write planes pre-barrier, h-waves RMW post ----
    if (w < 4){
#pragma unroll
      for (int cI = 0; cI < 2; ++cI)
#pragma unroll
        for (int rb = 0; rb < 2; ++rb)
#pragma unroll
          for (int r = 0; r < 16; ++r){
            int row = rb*32 + (r&3) + 8*(r>>2) + 4*rsel;
            planes[w][row][cI*32 + col] = acc[cI][rb][r];
          }
    }
    __syncthreads();   // B1
    if (w >= 4){
#pragma unroll
      for (int cI = 0; cI < 2; ++cI)
#pragma unroll
        for (int rb = 0; rb < 2; ++rb)
#pragma unroll
          for (int r = 0; r < 16; ++r){
            int row = rb*32 + (r&3) + 8*(r>>2) + 4*rsel;
            planes[w-4][row][cI*32 + col] += acc[cI][rb][r];
          }
    }
    __syncthreads();   // B2

    // ---- pointwise (all 512 threads) ----
    {
      float hn[2];
#pragma unroll
      for (int e = 0; e < 2; ++e){
        const int j = pj0 + e;
        float gv[4];
#pragma unroll
        for (int g = 0; g < 4; ++g){
          float s = bsm[g*16 + j];
          s += planes[0][prow][g*16 + j];
          s += planes[1][prow][g*16 + j];
          s += planes[2][prow][g*16 + j];
          s += planes[3][prow][g*16 + j];
          gv[g] = s;
        }
        float cp = cst[prow][j];
        float cn = sigf(gv[1])*cp + sigf(gv[0])*tanhf2(gv[2]);
        float hv = sigf(gv[3])*tanhf2(cn);
        cst[prow][j] = cn;
        hn[e] = hv;
      }
      hf0 = hn[0]; hf1 = hn[1];
      const int kg = lblk*2 + (pj0>>3);
      const size_t fo = ((size_t)kg*64 + prow)*8 + (pj0&7);
      if (l == 0){
        stu(hseq0 + (size_t)(t+1)*SLOTS + fo, packbf2(hn[0], hn[1]));
      } else {
        size_t slot = use_seq1 ? (size_t)(t+1)*SLOTS : (size_t)(t&1)*SLOTS;
        stu(h1buf + slot + fo, packbf2(hn[0], hn[1]));
        float* dp = dout + ((size_t)prow*SEQ + t)*HID + lblk*DPB + pj0;
        dp[0] = hn[0]; dp[1] = hn[1];
      }
    }
    __syncthreads();   // B3: planes free for next step; stores drained (vmcnt0)
    if (tid == 0)
      __hip_atomic_store(myflag, (unsigned)t + 2u,
                         __ATOMIC_RELAXED, __HIP_MEMORY_SCOPE_AGENT);
  }

  // ---- epilogue: h_n / c_n ----
  {
    const size_t tb = (size_t)B64*SEQ*HID;
    size_t o = ((size_t)l*B64 + prow)*HID + lblk*DPB + pj0;
    float* hq = dout + tb + o;
    hq[0] = hf0; hq[1] = hf1;
    float* cq = dout + tb + (size_t)2*B64*HID + o;
    cq[0] = cst[prow][pj0]; cq[1] = cst[prow][pj0+1];
  }
}

// ---------------- host ----------------

extern "C" void kernel_launch(void* const* d_in, const int* in_sizes, int n_in,
                              void* d_out, int out_size, void* d_ws, size_t ws_size,
                              hipStream_t stream)
{
  const float* x  = (const float*)d_in[0];
  const float* Wi = (const float*)d_in[1];
  const float* bi = (const float*)d_in[2];
  const float* Wh = (const float*)d_in[3];
  const float* bh = (const float*)d_in[4];
  const float* h0 = (const float*)d_in[5];
  const float* c0 = (const float*)d_in[6];
  float* out = (float*)d_out;

  char* ws = (char*)d_ws;
  unsigned* flags0 = (unsigned*)ws;              // 64 u32 @ 0
  unsigned* flags1 = (unsigned*)(ws + 2048);     // 64 u32 @ 2048
  float*    bsum   = (float*)(ws + 4096);        // 32 KB
  short*    wT     = (short*)(ws + 65536);       // 32 MB

  const size_t hseq_bytes = (size_t)(SEQ+1)*SLOTS*2;   // ~64.1 MB
  size_t off = 65536 + (size_t)2*NG*KTOT*2;            // end of wT
  short* hseq0 = (short*)(ws + off); off += hseq_bytes;

  int use_seq1 = 0;
  short* h1buf = (short*)(ws + off);
  if (ws_size >= off + hseq_bytes){ use_seq1 = 1; off += hseq_bytes; }
  else {
    if (ws_size < off + (size_t)2*SLOTS*2) return;     // can't run at all
    off += (size_t)2*SLOTS*2;                          // parity fallback 256 KB
  }

  int use_xbf = 0; short* xbf = (short*)(ws + off);
  if (ws_size >= off + (size_t)B64*SEQ*HID*2) use_xbf = 1;

  lstm_prep<<<32, 256, 0, stream>>>(bi, bh, bsum, flags0);
  lstm_tr<<<dim3(128, 32, 4), 256, 0, stream>>>(Wi, Wh, wT);
  if (use_xbf) lstm_xbf<<<16384, 256, 0, stream>>>(x, xbf);
  lstm_main<<<128, 512, 0, stream>>>(x, h0, c0, out, wT, bsum, hseq0, h1buf,
                                     flags0, flags1, xbf, use_xbf, use_seq1);
}

// Round 4
// 5458.324 us; speedup vs baseline: 5.6625x; 1.3113x over previous
//
#include <hip/hip_runtime.h>
#include <hip/hip_bf16.h>

// LSTM B=64 L=512 H=1024 x2, persistent kernel v4.
// v4 vs v3:
//  - poller-wave + LDS epoch broadcast: ONE wave per wait-condition polls the
//    global flags (agent-scope, L2-bypass); sibling waves spin on an LDS word.
//    Cuts global wave-pollers 512 -> 192 (v3's poll-storm on 4 LLC lines).
//  - x pre-transposed to fragment layout xfrag[t][kg][row][8] bf16: in-loop
//    x loads become identical to the coalesced h loads (v3 read 16B/lane at
//    1MB stride = 32 lines/instr, ~4k TA cycles/CU/step + straggler jitter).
//  - protocol, layouts, pipelined layers otherwise unchanged from v3.

#define B64  64
#define SEQ  512
#define HID  1024
#define KTOT 2048
#define NG   4096
#define DPB  16
#define SLOTS 65536   // shorts per frag slot = 128 kg * 64 rows * 8

typedef __attribute__((ext_vector_type(8)))  short short8;
typedef __attribute__((ext_vector_type(16))) float f32x16;

__device__ inline short bfo(float v){
  __hip_bfloat16 h = __float2bfloat16(v);
  short s; __builtin_memcpy(&s, &h, 2); return s;
}
__device__ inline unsigned packbf2(float a, float b){
  return (unsigned)(unsigned short)bfo(a) | ((unsigned)(unsigned short)bfo(b) << 16);
}
__device__ inline short8 cvt8(float4 a, float4 b){
  short8 r;
  r[0]=bfo(a.x); r[1]=bfo(a.y); r[2]=bfo(a.z); r[3]=bfo(a.w);
  r[4]=bfo(b.x); r[5]=bfo(b.y); r[6]=bfo(b.z); r[7]=bfo(b.w);
  return r;
}
__device__ inline float sigf(float v){ return 1.f/(1.f + __expf(-v)); }
__device__ inline float tanhf2(float v){
  float a = fabsf(v);
  float e = __expf(-2.f*a);
  float r = (1.f-e)/(1.f+e);
  return v < 0.f ? -r : r;
}
__device__ inline f32x16 MFMA(short8 a, short8 b, f32x16 c){
  return __builtin_amdgcn_mfma_f32_32x32x16_bf16(a, b, c, 0, 0, 0);
}

// LLC-coherent helpers
__device__ inline short8 ldh8(const short* p){
  unsigned long long a = __hip_atomic_load((const unsigned long long*)p,
                          __ATOMIC_RELAXED, __HIP_MEMORY_SCOPE_AGENT);
  unsigned long long b = __hip_atomic_load((const unsigned long long*)(p+4),
                          __ATOMIC_RELAXED, __HIP_MEMORY_SCOPE_AGENT);
  short8 r;
  __builtin_memcpy(&r, &a, 8);
  __builtin_memcpy(((char*)&r)+8, &b, 8);
  return r;
}
__device__ inline void stu(short* p, unsigned v){
  __hip_atomic_store((unsigned*)p, v, __ATOMIC_RELAXED, __HIP_MEMORY_SCOPE_AGENT);
}

__device__ inline void waitflags(const unsigned* flags, unsigned e, int lane){
  const unsigned* p = flags + lane;
  for(;;){
    unsigned a = __hip_atomic_load(p, __ATOMIC_RELAXED, __HIP_MEMORY_SCOPE_AGENT);
    if (__all(a >= e)) break;
    __builtin_amdgcn_s_sleep(1);
  }
  asm volatile("" ::: "memory");
}
__device__ inline void lds_pub(int* p, int v){
  __hip_atomic_store(p, v, __ATOMIC_RELAXED, __HIP_MEMORY_SCOPE_WORKGROUP);
}
__device__ inline void lds_spin(int* p, int v){
  while (__hip_atomic_load(p, __ATOMIC_RELAXED, __HIP_MEMORY_SCOPE_WORKGROUP) < v)
    __builtin_amdgcn_s_sleep(1);
  asm volatile("" ::: "memory");
}

// ---------------- prologue kernels ----------------

__global__ void lstm_prep(const float* __restrict__ bi, const float* __restrict__ bh,
                          float* __restrict__ bsum, unsigned* __restrict__ flagpage)
{
  int i = blockIdx.x*256 + threadIdx.x;
  if (i < 1024) flagpage[i] = 0;          // flags0 @0, flags1 @2048B
  if (i < 2*NG) bsum[i] = bi[i] + bh[i];
}

// W_i/W_h [2][1024][4096] f32 -> wT [2][4096][2048] bf16 (gate-col major, k inner)
__global__ void lstm_tr(const float* __restrict__ Wi, const float* __restrict__ Wh,
                        short* __restrict__ wT)
{
  __shared__ float tile[32][33];
  const int z = blockIdx.z, l = z >> 1, s = z & 1;
  const float* W = (s ? Wh : Wi) + (size_t)l*1024*4096;
  const int k0 = blockIdx.y*32, n0 = blockIdx.x*32;
  const int tx = threadIdx.x & 31, ty = threadIdx.x >> 5;
#pragma unroll
  for (int i = 0; i < 32; i += 8)
    tile[ty+i][tx] = W[(size_t)(k0+ty+i)*4096 + n0 + tx];
  __syncthreads();
#pragma unroll
  for (int i = 0; i < 32; i += 8)
    wT[((size_t)l*NG + n0+ty+i)*KTOT + s*1024 + k0 + tx] = bfo(tile[tx][ty+i]);
}

// x [64][512][1024] f32 -> xfrag [512][128 kg][64 r][8] bf16
// thread: full-64B-line read (16 f32), two coalesced 16B frag writes
__global__ void lstm_xfrag(const float* __restrict__ x, short* __restrict__ xf)
{
  const int t = blockIdx.x, kgb = blockIdx.y;          // grid (512, 16)
  const int r = threadIdx.x & 63, kq = threadIdx.x >> 6;
  const int kg = kgb*8 + kq*2;
  const float* p = x + ((size_t)r*SEQ + t)*1024 + kg*8;
  float4 a = *(const float4*)p,      b = *(const float4*)(p+4);
  float4 c = *(const float4*)(p+8),  d = *(const float4*)(p+12);
  short* q = xf + (((size_t)t*128 + kg)*64 + r)*8;
  *(short8*)q            = cvt8(a, b);
  *(short8*)(q + 64*8)   = cvt8(c, d);
}

// ---------------- main persistent kernel ----------------

__global__ void __launch_bounds__(512, 1)
lstm_main(const float* __restrict__ x,
          const float* __restrict__ h0in,
          const float* __restrict__ c0in,
          float* __restrict__ dout,
          const short* __restrict__ wT,
          const float* __restrict__ bsum,
          short* __restrict__ hseq0,
          short* __restrict__ h1buf,
          unsigned* __restrict__ flags0,
          unsigned* __restrict__ flags1,
          const short* __restrict__ xf,
          int use_xf, int use_seq1)
{
  const int blk  = blockIdx.x;     // 128 blocks
  const int l    = blk & 1;        // layer
  const int lblk = blk >> 1;       // 0..63, owns dims [lblk*16, +16)
  const int tid  = threadIdx.x;
  const int lane = tid & 63;
  const int w    = tid >> 6;       // k-eighth: w<4 = x-part, w>=4 = h-part
  const int col  = lane & 31;
  const int rsel = lane >> 5;

  __shared__ float planes[4][64][68];
  __shared__ float cst[64][17];
  __shared__ float bsm[64];
  __shared__ int   eps[2];          // [0]=x-cond epoch (layer1), [1]=h-cond epoch

  const int prow = tid >> 3;
  const int pj0  = (tid & 7) * 2;

  __builtin_amdgcn_fence(__ATOMIC_ACQUIRE, "agent");

  unsigned* myflag = (l ? flags1 : flags0) + lblk;

  // ---- init ----
  if (tid < 64) bsm[tid] = bsum[l*NG + (tid>>4)*HID + lblk*DPB + (tid&15)];
  if (tid < 2)  eps[tid] = -1;
  {
    size_t o = ((size_t)l*B64 + prow)*HID + lblk*DPB + pj0;
    cst[prow][pj0]   = c0in[o];
    cst[prow][pj0+1] = c0in[o+1];
    const int kg = lblk*2 + (pj0>>3);
    short* hm1 = l ? (h1buf + (use_seq1 ? (size_t)0 : (size_t)SLOTS)) : hseq0;
    stu(hm1 + ((size_t)kg*64 + prow)*8 + (pj0&7), packbf2(h0in[o], h0in[o+1]));
  }
  short8 bf[2][16];
  {
    const short* wl = wT + (size_t)l*NG*KTOT;
#pragma unroll
    for (int cI = 0; cI < 2; ++cI){
      const int c  = cI*32 + col;
      const int gc = (c>>4)*HID + lblk*DPB + (c&15);
      const short* wp = wl + (size_t)gc*KTOT + w*256 + rsel*8;
#pragma unroll
      for (int s = 0; s < 16; ++s)
        bf[cI][s] = *(const short8*)(wp + s*16);
    }
  }
  __syncthreads();   // drains vmcnt: init write-through stores are in LLC
  if (tid == 0)
    __hip_atomic_store(myflag, 1u, __ATOMIC_RELAXED, __HIP_MEMORY_SCOPE_AGENT);

  float hf0 = 0.f, hf1 = 0.f;

  for (int t = 0; t < SEQ; ++t){
    f32x16 acc[2][2];
#pragma unroll
    for (int a = 0; a < 2; ++a)
#pragma unroll
      for (int b = 0; b < 2; ++b)
#pragma unroll
        for (int i = 0; i < 16; ++i) acc[a][b][i] = 0.f;

    // ---- wait phase (poller wave -> LDS epoch; siblings spin LDS) ----
    if (l == 0){
      if (w == 4){ waitflags(flags0, (unsigned)t + 1u, lane); if (lane == 0) lds_pub(&eps[1], t); }
      else if (w > 4){ lds_spin(&eps[1], t); }
    } else {
      if (w == 0){ waitflags(flags0, (unsigned)t + 2u, lane); if (lane == 0) lds_pub(&eps[0], t); }
      else if (w < 4){ lds_spin(&eps[0], t); }
      else if (w == 4){ waitflags(flags1, (unsigned)t + 1u, lane); if (lane == 0) lds_pub(&eps[1], t); }
      else { lds_spin(&eps[1], t); }
    }

    // ---- A-source (fragment layout for all fast paths) ----
    const short* ap = nullptr;
    if (w < 4) ap = (l == 0) ? (use_xf ? xf + (size_t)t*SLOTS : nullptr)
                             : hseq0 + (size_t)(t+1)*SLOTS;
    else       ap = (l == 0) ? hseq0 + (size_t)t*SLOTS
                             : (use_seq1 ? h1buf + (size_t)t*SLOTS : nullptr);
    const int kgbase = (w & 3) * 32;

    if (ap){
#pragma unroll
      for (int s = 0; s < 16; ++s){
        const int kg = kgbase + s*2 + rsel;
        short8 a0 = *(const short8*)(ap + ((size_t)kg*64 + col)*8);
        short8 a1 = *(const short8*)(ap + ((size_t)kg*64 + 32 + col)*8);
        acc[0][0] = MFMA(a0, bf[0][s], acc[0][0]);
        acc[0][1] = MFMA(a1, bf[0][s], acc[0][1]);
        acc[1][0] = MFMA(a0, bf[1][s], acc[1][0]);
        acc[1][1] = MFMA(a1, bf[1][s], acc[1][1]);
      }
    } else if (w < 4){
      // fallback: raw f32 x (scattered)
      const float* p0 = x + ((size_t)col*SEQ + t)*HID + w*256 + rsel*8;
      const float* p1 = p0 + (size_t)32*SEQ*HID;
#pragma unroll
      for (int s = 0; s < 16; ++s){
        short8 a0 = cvt8(*(const float4*)(p0 + s*16), *(const float4*)(p0 + s*16 + 4));
        short8 a1 = cvt8(*(const float4*)(p1 + s*16), *(const float4*)(p1 + s*16 + 4));
        acc[0][0] = MFMA(a0, bf[0][s], acc[0][0]);
        acc[0][1] = MFMA(a1, bf[0][s], acc[0][1]);
        acc[1][0] = MFMA(a0, bf[1][s], acc[1][0]);
        acc[1][1] = MFMA(a1, bf[1][s], acc[1][1]);
      }
    } else {
      // fallback: layer-1 parity h buffer (LLC-bypass loads)
      const short* hs = h1buf + (size_t)((t+1)&1)*SLOTS;
#pragma unroll
      for (int s = 0; s < 16; ++s){
        const int kg = kgbase + s*2 + rsel;
        short8 a0 = ldh8(hs + ((size_t)kg*64 + col)*8);
        short8 a1 = ldh8(hs + ((size_t)kg*64 + 32 + col)*8);
        acc[0][0] = MFMA(a0, bf[0][s], acc[0][0]);
        acc[0][1] = MFMA(a1, bf[0][s], acc[0][1]);
        acc[1][0] = MFMA(a0, bf[1][s], acc[1][0]);
        acc[1][1] = MFMA(a1, bf[1][s], acc[1][1]);
      }
    }

    // ---- reduction ----
    if (w < 4){
#pragma unroll
      for (int cI = 0; cI < 2; ++cI)
#pragma unroll
        for (int rb = 0; rb < 2; ++rb)
#pragma unroll
          for (int r = 0; r < 16; ++r){
            int row = rb*32 + (r&3) + 8*(r>>2) + 4*rsel;
            planes[w][row][cI*32 + col] = acc[cI][rb][r];
          }
    }
    __syncthreads();   // B1
    if (w >= 4){
#pragma unroll
      for (int cI = 0; cI < 2; ++cI)
#pragma unroll
        for (int rb = 0; rb < 2; ++rb)
#pragma unroll
          for (int r = 0; r < 16; ++r){
            int row = rb*32 + (r&3) + 8*(r>>2) + 4*rsel;
            planes[w-4][row][cI*32 + col] += acc[cI][rb][r];
          }
    }
    __syncthreads();   // B2

    // ---- pointwise ----
    {
      float hn[2];
#pragma unroll
      for (int e = 0; e < 2; ++e){
        const int j = pj0 + e;
        float gv[4];
#pragma unroll
        for (int g = 0; g < 4; ++g){
          float s = bsm[g*16 + j];
          s += planes[0][prow][g*16 + j];
          s += planes[1][prow][g*16 + j];
          s += planes[2][prow][g*16 + j];
          s += planes[3][prow][g*16 + j];
          gv[g] = s;
        }
        float cp = cst[prow][j];
        float cn = sigf(gv[1])*cp + sigf(gv[0])*tanhf2(gv[2]);
        float hv = sigf(gv[3])*tanhf2(cn);
        cst[prow][j] = cn;
        hn[e] = hv;
      }
      hf0 = hn[0]; hf1 = hn[1];
      const int kg = lblk*2 + (pj0>>3);
      const size_t fo = ((size_t)kg*64 + prow)*8 + (pj0&7);
      if (l == 0){
        stu(hseq0 + (size_t)(t+1)*SLOTS + fo, packbf2(hn[0], hn[1]));
      } else {
        size_t slot = use_seq1 ? (size_t)(t+1)*SLOTS : (size_t)(t&1)*SLOTS;
        stu(h1buf + slot + fo, packbf2(hn[0], hn[1]));
        float* dp = dout + ((size_t)prow*SEQ + t)*HID + lblk*DPB + pj0;
        dp[0] = hn[0]; dp[1] = hn[1];
      }
    }
    __syncthreads();   // B3: planes reusable; all waves' stores drained (vmcnt0)
    if (tid == 0)
      __hip_atomic_store(myflag, (unsigned)t + 2u,
                         __ATOMIC_RELAXED, __HIP_MEMORY_SCOPE_AGENT);
  }

  // ---- epilogue: h_n / c_n ----
  {
    const size_t tb = (size_t)B64*SEQ*HID;
    size_t o = ((size_t)l*B64 + prow)*HID + lblk*DPB + pj0;
    float* hq = dout + tb + o;
    hq[0] = hf0; hq[1] = hf1;
    float* cq = dout + tb + (size_t)2*B64*HID + o;
    cq[0] = cst[prow][pj0]; cq[1] = cst[prow][pj0+1];
  }
}

// ---------------- host ----------------

extern "C" void kernel_launch(void* const* d_in, const int* in_sizes, int n_in,
                              void* d_out, int out_size, void* d_ws, size_t ws_size,
                              hipStream_t stream)
{
  const float* x  = (const float*)d_in[0];
  const float* Wi = (const float*)d_in[1];
  const float* bi = (const float*)d_in[2];
  const float* Wh = (const float*)d_in[3];
  const float* bh = (const float*)d_in[4];
  const float* h0 = (const float*)d_in[5];
  const float* c0 = (const float*)d_in[6];
  float* out = (float*)d_out;

  char* ws = (char*)d_ws;
  unsigned* flags0 = (unsigned*)ws;              // 64 u32 @ 0
  unsigned* flags1 = (unsigned*)(ws + 2048);     // 64 u32 @ 2048
  float*    bsum   = (float*)(ws + 4096);        // 32 KB
  short*    wT     = (short*)(ws + 65536);       // 32 MB

  const size_t hseq_bytes = (size_t)(SEQ+1)*SLOTS*2;   // ~64.1 MB
  size_t off = 65536 + (size_t)2*NG*KTOT*2;            // end of wT
  short* hseq0 = (short*)(ws + off); off += hseq_bytes;

  int use_seq1 = 0;
  short* h1buf = (short*)(ws + off);
  if (ws_size >= off + hseq_bytes){ use_seq1 = 1; off += hseq_bytes; }
  else {
    if (ws_size < off + (size_t)2*SLOTS*2) return;
    off += (size_t)2*SLOTS*2;
  }

  int use_xf = 0; short* xf = (short*)(ws + off);
  if (ws_size >= off + (size_t)SEQ*SLOTS*2) use_xf = 1;  // 64 MB

  lstm_prep<<<32, 256, 0, stream>>>(bi, bh, bsum, flags0);
  lstm_tr<<<dim3(128, 32, 4), 256, 0, stream>>>(Wi, Wh, wT);
  if (use_xf) lstm_xfrag<<<dim3(512, 16), 256, 0, stream>>>(x, xf);
  lstm_main<<<128, 512, 0, stream>>>(x, h0, c0, out, wT, bsum, hseq0, h1buf,
                                     flags0, flags1, xf, use_xf, use_seq1);
}

// Round 6
// 4195.481 us; speedup vs baseline: 7.3669x; 1.3010x over previous
//
#include <hip/hip_runtime.h>
#include <hip/hip_bf16.h>

// LSTM B=64 L=512 H=1024 x2, persistent kernel v6.
// v6 vs v5: SLOT32 corrected 8192 -> 32768 (v5's slots aliased 4x: the bug).
//   Restored v4-style fallbacks: h1seq full-seq if ws allows, else 2-slot ring
//   with FULL-DOMAIN wait + 8B bypass loads; xf frag if ws allows, else f32 x.
// Design (from v5): 256 blocks = 2 layers x 2 row-halves (M=32) x 64 col-blocks;
//   4 independent sync domains; W dup x2 in VGPRs (128/wave); per-WAVE producer
//   flags posted after wave-local vmcnt(0) (no block barrier on flag path);
//   2-phase 128-flag consumer waits; planes stride 65.

#define B64  64
#define SEQ  512
#define HID  1024
#define KTOT 2048
#define NG   4096
#define DPB  16
#define SLOT32 32768           // shorts per (t, rhalf) frag slot = 128kg*32r*8
#define NSLOT (SEQ+1)

typedef __attribute__((ext_vector_type(8)))  short short8;
typedef __attribute__((ext_vector_type(16))) float f32x16;

__device__ inline short bfo(float v){
  __hip_bfloat16 h = __float2bfloat16(v);
  short s; __builtin_memcpy(&s, &h, 2); return s;
}
__device__ inline unsigned packbf2(float a, float b){
  return (unsigned)(unsigned short)bfo(a) | ((unsigned)(unsigned short)bfo(b) << 16);
}
__device__ inline short8 cvt8(float4 a, float4 b){
  short8 r;
  r[0]=bfo(a.x); r[1]=bfo(a.y); r[2]=bfo(a.z); r[3]=bfo(a.w);
  r[4]=bfo(b.x); r[5]=bfo(b.y); r[6]=bfo(b.z); r[7]=bfo(b.w);
  return r;
}
__device__ inline float sigf(float v){ return 1.f/(1.f + __expf(-v)); }
__device__ inline float tanhf2(float v){
  float a = fabsf(v);
  float e = __expf(-2.f*a);
  float r = (1.f-e)/(1.f+e);
  return v < 0.f ? -r : r;
}
__device__ inline f32x16 MFMA(short8 a, short8 b, f32x16 c){
  return __builtin_amdgcn_mfma_f32_32x32x16_bf16(a, b, c, 0, 0, 0);
}
__device__ inline void stu(short* p, unsigned v){
  __hip_atomic_store((unsigned*)p, v, __ATOMIC_RELAXED, __HIP_MEMORY_SCOPE_AGENT);
}
__device__ inline void st8f(float* p, float a, float b){
  unsigned ua, ub; __builtin_memcpy(&ua, &a, 4); __builtin_memcpy(&ub, &b, 4);
  unsigned long long v = (unsigned long long)ua | ((unsigned long long)ub << 32);
  __hip_atomic_store((unsigned long long*)p, v, __ATOMIC_RELAXED, __HIP_MEMORY_SCOPE_AGENT);
}
__device__ inline unsigned pollld(const unsigned* p){
  return __hip_atomic_load(p, __ATOMIC_RELAXED, __HIP_MEMORY_SCOPE_AGENT);
}
__device__ inline short8 ldh8(const short* p){
  unsigned long long a = __hip_atomic_load((const unsigned long long*)p,
                          __ATOMIC_RELAXED, __HIP_MEMORY_SCOPE_AGENT);
  unsigned long long b = __hip_atomic_load((const unsigned long long*)(p+4),
                          __ATOMIC_RELAXED, __HIP_MEMORY_SCOPE_AGENT);
  short8 r;
  __builtin_memcpy(&r, &a, 8);
  __builtin_memcpy(((char*)&r)+8, &b, 8);
  return r;
}

// wait all 512 flags of a domain >= e (ring-fallback path only)
__device__ inline void waitflags_all(const unsigned* f, unsigned e, int lane){
  for(;;){
    unsigned a0 = pollld(f + lane),       a1 = pollld(f + 64 + lane);
    unsigned a2 = pollld(f + 128 + lane), a3 = pollld(f + 192 + lane);
    unsigned a4 = pollld(f + 256 + lane), a5 = pollld(f + 320 + lane);
    unsigned a6 = pollld(f + 384 + lane), a7 = pollld(f + 448 + lane);
    bool ok = (a0>=e)&&(a1>=e)&&(a2>=e)&&(a3>=e)&&(a4>=e)&&(a5>=e)&&(a6>=e)&&(a7>=e);
    if (__all(ok)) break;
    __builtin_amdgcn_s_sleep(1);
  }
  asm volatile("" ::: "memory");
}

// A-panel GEMM: K=256 eighth, 16 kg-pairs, 2-phase wait over 128 producer flags.
__device__ inline void gemmA_wait(const short* __restrict__ slot,
                                  const unsigned* __restrict__ win, unsigned e,
                                  int lane, int kgbase,
                                  const short8 (&bf)[2][16], f32x16& a0, f32x16& a1)
{
  const int row = lane & 31, ksel = lane >> 5;
  const unsigned* p0 = win + lane;
  const unsigned* p1 = win + 64 + lane;
  unsigned f1;
  for(;;){
    unsigned f0 = pollld(p0); f1 = pollld(p1);
    if (__all(f0 >= e)) break;
    __builtin_amdgcn_s_sleep(1);
  }
  asm volatile("" ::: "memory");
#pragma unroll
  for (int s = 0; s < 8; ++s){
    const short8 a = *(const short8*)(slot + ((size_t)(kgbase + s*2 + ksel)*32 + row)*8);
    a0 = MFMA(a, bf[0][s], a0);
    a1 = MFMA(a, bf[1][s], a1);
  }
  while (!__all(f1 >= e)){ __builtin_amdgcn_s_sleep(1); f1 = pollld(p1); }
  asm volatile("" ::: "memory");
#pragma unroll
  for (int s = 8; s < 16; ++s){
    const short8 a = *(const short8*)(slot + ((size_t)(kgbase + s*2 + ksel)*32 + row)*8);
    a0 = MFMA(a, bf[0][s], a0);
    a1 = MFMA(a, bf[1][s], a1);
  }
}
__device__ inline void gemmA_now(const short* __restrict__ slot, int lane, int kgbase,
                                 const short8 (&bf)[2][16], f32x16& a0, f32x16& a1)
{
  const int row = lane & 31, ksel = lane >> 5;
#pragma unroll
  for (int s = 0; s < 16; ++s){
    const short8 a = *(const short8*)(slot + ((size_t)(kgbase + s*2 + ksel)*32 + row)*8);
    a0 = MFMA(a, bf[0][s], a0);
    a1 = MFMA(a, bf[1][s], a1);
  }
}
__device__ inline void gemmA_bp(const short* __restrict__ slot, int lane, int kgbase,
                                const short8 (&bf)[2][16], f32x16& a0, f32x16& a1)
{
  const int row = lane & 31, ksel = lane >> 5;
#pragma unroll
  for (int s = 0; s < 16; ++s){
    const short8 a = ldh8(slot + ((size_t)(kgbase + s*2 + ksel)*32 + row)*8);
    a0 = MFMA(a, bf[0][s], a0);
    a1 = MFMA(a, bf[1][s], a1);
  }
}

// ---------------- prologue kernels ----------------

__global__ void lstm_prep(const float* __restrict__ bi, const float* __restrict__ bh,
                          float* __restrict__ bsum, unsigned* __restrict__ flags)
{
  int i = blockIdx.x*256 + threadIdx.x;
  if (i < 4096) flags[i] = 0;            // 4 domains x 512 wave-flags
  if (i < 2*NG) bsum[i] = bi[i] + bh[i];
}

// W_i/W_h [2][1024][4096] f32 -> wT [2][4096][2048] bf16 (gate-col major, k inner)
__global__ void lstm_tr(const float* __restrict__ Wi, const float* __restrict__ Wh,
                        short* __restrict__ wT)
{
  __shared__ float tile[32][33];
  const int z = blockIdx.z, l = z >> 1, s = z & 1;
  const float* W = (s ? Wh : Wi) + (size_t)l*1024*4096;
  const int k0 = blockIdx.y*32, n0 = blockIdx.x*32;
  const int tx = threadIdx.x & 31, ty = threadIdx.x >> 5;
#pragma unroll
  for (int i = 0; i < 32; i += 8)
    tile[ty+i][tx] = W[(size_t)(k0+ty+i)*4096 + n0 + tx];
  __syncthreads();
#pragma unroll
  for (int i = 0; i < 32; i += 8)
    wT[((size_t)l*NG + n0+ty+i)*KTOT + s*1024 + k0 + tx] = bfo(tile[tx][ty+i]);
}

// x [64][512][1024] f32 -> xf [512][2 rh][128 kg][32 r][8] bf16
__global__ void lstm_xfrag(const float* __restrict__ x, short* __restrict__ xf)
{
  const int t = blockIdx.x;
  const int rh = blockIdx.y >> 4, kgb = blockIdx.y & 15;   // grid (512, 32)
  const int r = threadIdx.x >> 3, kq = threadIdx.x & 7;
  const int kg = kgb*8 + kq;
  const int grow = rh*32 + r;
  const float* p = x + ((size_t)grow*SEQ + t)*HID + kg*8;
  float4 a = *(const float4*)p, b = *(const float4*)(p + 4);
  *(short8*)(xf + ((size_t)t*2 + rh)*SLOT32 + ((size_t)kg*32 + r)*8) = cvt8(a, b);
}

// ---------------- main persistent kernel ----------------

__global__ void __launch_bounds__(512, 1)
lstm_main(const float* __restrict__ x,
          const float* __restrict__ h0in,
          const float* __restrict__ c0in,
          float* __restrict__ dout,
          const short* __restrict__ wT,
          const float* __restrict__ bsum,
          short* __restrict__ hseq0,
          short* __restrict__ h1seq,
          unsigned* __restrict__ flags,
          const short* __restrict__ xf,
          int use_xf, int use_seq1)
{
  const int blk  = blockIdx.x;          // 256 blocks
  const int l    = blk & 1;             // layer
  const int rh   = (blk >> 1) & 1;      // row half (rows rh*32..+32)
  const int lblk = blk >> 2;            // 0..63, owns dims [lblk*16,+16)
  const int dom  = blk & 3;             // sync domain = (rh,l)
  const int dom0 = 2*rh;                // layer-0 domain of same row half
  const int tid  = threadIdx.x;
  const int lane = tid & 63;
  const int w    = tid >> 6;            // K-eighth: w<4 = x-part, w>=4 = h-part
  const int c31  = lane & 31;

  __shared__ float planes[4][32][65];   // gate partials [plane][row][64 cols+pad]
  __shared__ float cst[32][17];
  __shared__ float bsm[64];

  __builtin_amdgcn_fence(__ATOMIC_ACQUIRE, "agent");   // once: drop stale lines

  unsigned* dflag = flags + dom*512;                   // [64 blk][8 w]
  unsigned* myflag = dflag + lblk*8 + w;

  // ---- init ----
  if (tid < 64) bsm[tid] = bsum[l*NG + (tid>>4)*HID + lblk*DPB + (tid&15)];
  if (lane < 32){
    const int r = lane;
    const int grow = rh*32 + r;
    size_t o = ((size_t)l*B64 + grow)*HID + lblk*DPB + w*2;
    cst[r][w*2]   = c0in[o];
    cst[r][w*2+1] = c0in[o+1];
    const int kg = lblk*2 + (w>>2);
    short* hm1 = (l ? h1seq : hseq0) + (size_t)rh*SLOT32;   // slot 0 (both modes)
    stu(hm1 + ((size_t)kg*32 + r)*8 + ((w*2)&7), packbf2(h0in[o], h0in[o+1]));
  }
  // persistent B fragments: 64 cols x 256 k = 128 VGPRs
  short8 bf[2][16];
  {
    const short* wl = wT + (size_t)l*NG*KTOT;
#pragma unroll
    for (int cI = 0; cI < 2; ++cI){
      const int c  = cI*32 + c31;
      const int gc = (c>>4)*HID + lblk*DPB + (c&15);
      const short* wp = wl + (size_t)gc*KTOT + w*256 + (lane>>5)*8;
#pragma unroll
      for (int s = 0; s < 16; ++s)
        bf[cI][s] = *(const short8*)(wp + s*16);
    }
  }
  __syncthreads();    // all waves drained vmcnt before barrier -> init stores in LLC
  if (lane == 0)
    __hip_atomic_store(myflag, 1u, __ATOMIC_RELAXED, __HIP_MEMORY_SCOPE_AGENT);

  float hf0 = 0.f, hf1 = 0.f;

  for (int t = 0; t < SEQ; ++t){
    f32x16 a0, a1;
#pragma unroll
    for (int i = 0; i < 16; ++i){ a0[i] = 0.f; a1[i] = 0.f; }

    if (w < 4){
      // ---- x-part ----
      if (l == 0){
        if (use_xf){
          gemmA_now(xf + ((size_t)t*2 + rh)*SLOT32, lane, w*32, bf, a0, a1);
        } else {
          const int row = lane & 31, ksel = lane >> 5;
          const int grow = rh*32 + row;
          const float* p = x + ((size_t)grow*SEQ + t)*HID;
#pragma unroll
          for (int s = 0; s < 16; ++s){
            const int kg = w*32 + s*2 + ksel;
            short8 a = cvt8(*(const float4*)(p + kg*8), *(const float4*)(p + kg*8 + 4));
            a0 = MFMA(a, bf[0][s], a0);
            a1 = MFMA(a, bf[1][s], a1);
          }
        }
      } else {
        // layer-1 input = h0(t): hseq0 slot t+1, wait layer-0 window flags
        gemmA_wait(hseq0 + ((size_t)(t+1)*2 + rh)*SLOT32,
                   flags + dom0*512 + w*128, (unsigned)t + 2u,
                   lane, w*32, bf, a0, a1);
      }
    } else {
      // ---- h-part: own layer h(t-1) ----
      if (l == 0){
        gemmA_wait(hseq0 + ((size_t)t*2 + rh)*SLOT32,
                   dflag + (w-4)*128, (unsigned)t + 1u,
                   lane, (w-4)*32, bf, a0, a1);
      } else if (use_seq1){
        gemmA_wait(h1seq + ((size_t)t*2 + rh)*SLOT32,
                   dflag + (w-4)*128, (unsigned)t + 1u,
                   lane, (w-4)*32, bf, a0, a1);
      } else {
        // ring fallback: full-domain wait (ring overwrite needs ALL readers past
        // step t-1, not just this wave's producer window) + bypass loads
        waitflags_all(dflag, (unsigned)t + 1u, lane);
        gemmA_bp(h1seq + ((size_t)(t&1)*2 + rh)*SLOT32, lane, (w-4)*32, bf, a0, a1);
      }
    }

    // ---- reduction ----
    if (w < 4){
#pragma unroll
      for (int r = 0; r < 16; ++r){
        const int rr = (r&3) + 8*(r>>2) + 4*(lane>>5);
        planes[w][rr][c31]      = a0[r];
        planes[w][rr][32 + c31] = a1[r];
      }
    }
    __syncthreads();   // B1
    if (w >= 4){
#pragma unroll
      for (int r = 0; r < 16; ++r){
        const int rr = (r&3) + 8*(r>>2) + 4*(lane>>5);
        planes[w-4][rr][c31]      += a0[r];
        planes[w-4][rr][32 + c31] += a1[r];
      }
    }
    __syncthreads();   // B2

    // ---- pointwise: wave w owns dims {2w, 2w+1} x 32 rows (lanes 0-31) ----
    if (lane < 32){
      const int r = lane;
      float hn[2];
#pragma unroll
      for (int e = 0; e < 2; ++e){
        const int d = w*2 + e;
        float gv[4];
#pragma unroll
        for (int g = 0; g < 4; ++g){
          float s = bsm[g*16 + d];
          s += planes[0][r][g*16 + d];
          s += planes[1][r][g*16 + d];
          s += planes[2][r][g*16 + d];
          s += planes[3][r][g*16 + d];
          gv[g] = s;
        }
        float cp = cst[r][d];
        float cn = sigf(gv[1])*cp + sigf(gv[0])*tanhf2(gv[2]);
        float hv = sigf(gv[3])*tanhf2(cn);
        cst[r][d] = cn;
        hn[e] = hv;
      }
      hf0 = hn[0]; hf1 = hn[1];
      const int kg = lblk*2 + (w>>2);
      short* so;
      if (l == 0)           so = hseq0 + ((size_t)(t+1)*2 + rh)*SLOT32;
      else if (use_seq1)    so = h1seq + ((size_t)(t+1)*2 + rh)*SLOT32;
      else                  so = h1seq + ((size_t)((t+1)&1)*2 + rh)*SLOT32;
      stu(so + ((size_t)kg*32 + r)*8 + ((w*2)&7), packbf2(hn[0], hn[1]));
      if (l == 1){
        const int grow = rh*32 + r;
        st8f(dout + ((size_t)grow*SEQ + t)*HID + lblk*DPB + w*2, hn[0], hn[1]);
      }
    }
    asm volatile("s_waitcnt vmcnt(0)" ::: "memory");   // wave-local store ack
    if (lane == 0)
      __hip_atomic_store(myflag, (unsigned)t + 2u,
                         __ATOMIC_RELAXED, __HIP_MEMORY_SCOPE_AGENT);
    __syncthreads();   // B3: planes/cst reusable
  }

  // ---- epilogue: h_n / c_n ----
  if (lane < 32){
    const int r = lane;
    const int grow = rh*32 + r;
    const size_t tb = (size_t)B64*SEQ*HID;
    size_t o = ((size_t)l*B64 + grow)*HID + lblk*DPB + w*2;
    st8f(dout + tb + o, hf0, hf1);
    st8f(dout + tb + (size_t)2*B64*HID + o, cst[r][w*2], cst[r][w*2+1]);
  }
}

// ---------------- host ----------------

extern "C" void kernel_launch(void* const* d_in, const int* in_sizes, int n_in,
                              void* d_out, int out_size, void* d_ws, size_t ws_size,
                              hipStream_t stream)
{
  const float* x  = (const float*)d_in[0];
  const float* Wi = (const float*)d_in[1];
  const float* bi = (const float*)d_in[2];
  const float* Wh = (const float*)d_in[3];
  const float* bh = (const float*)d_in[4];
  const float* h0 = (const float*)d_in[5];
  const float* c0 = (const float*)d_in[6];
  float* out = (float*)d_out;

  char* ws = (char*)d_ws;
  unsigned* flags = (unsigned*)ws;                     // 16 KB (4 dom x 512)
  float*    bsum  = (float*)(ws + 16384);              // 32 KB
  short*    wT    = (short*)(ws + 131072);             // 32 MB

  const size_t wT_bytes  = (size_t)2*NG*KTOT*2;        // 33,554,432
  const size_t seq_bytes = (size_t)NSLOT*2*SLOT32*2;   // 513*2*32768*2 = 67.2 MB
  size_t off = 131072 + wT_bytes;

  short* hseq0 = (short*)(ws + off); off += seq_bytes; // required (~101 MB total)
  if (ws_size < off) return;

  int use_seq1 = 0;
  short* h1seq = (short*)(ws + off);
  if (ws_size >= off + seq_bytes){ use_seq1 = 1; off += seq_bytes; }
  else {
    if (ws_size < off + (size_t)2*2*SLOT32*2) return;  // 2-slot ring, 256 KB
    off += (size_t)2*2*SLOT32*2;
  }

  int use_xf = 0;
  short* xf = (short*)(ws + off);
  if (ws_size >= off + (size_t)SEQ*2*SLOT32*2) use_xf = 1;   // +67 MB

  lstm_prep<<<32, 256, 0, stream>>>(bi, bh, bsum, flags);
  lstm_tr<<<dim3(128, 32, 4), 256, 0, stream>>>(Wi, Wh, wT);
  if (use_xf) lstm_xfrag<<<dim3(SEQ, 32), 256, 0, stream>>>(x, xf);
  lstm_main<<<256, 512, 0, stream>>>(x, h0, c0, out, wT, bsum, hseq0, h1seq,
                                     flags, xf, use_xf, use_seq1);
}

// Round 7
// 3399.563 us; speedup vs baseline: 9.0917x; 1.2341x over previous
//
#include <hip/hip_runtime.h>
#include <hip/hip_bf16.h>

// LSTM B=64 L=512 H=1024 x2, persistent kernel v7.
// v7 vs v6 (protocol slots/windows unchanged):
//  - ONE flag per block (posted by tid0 after B3; __syncthreads drains vmcnt).
//    Consumer window = 16 flags = ONE 64B line; ballot-split 8+8 chunks.
//  - 8 planes (one per wave, direct write): B1 barrier + LDS RMW pass deleted.
//    2 barriers/step instead of 3.
//  - busy-poll (no s_sleep): detect at natural ~RTT period.
//  - layer-1 dout store deferred to after the flag post (off critical path).

#define B64  64
#define SEQ  512
#define HID  1024
#define KTOT 2048
#define NG   4096
#define DPB  16
#define SLOT32 32768           // shorts per (t, rhalf) frag slot = 128kg*32r*8
#define NSLOT (SEQ+1)

typedef __attribute__((ext_vector_type(8)))  short short8;
typedef __attribute__((ext_vector_type(16))) float f32x16;

__device__ inline short bfo(float v){
  __hip_bfloat16 h = __float2bfloat16(v);
  short s; __builtin_memcpy(&s, &h, 2); return s;
}
__device__ inline unsigned packbf2(float a, float b){
  return (unsigned)(unsigned short)bfo(a) | ((unsigned)(unsigned short)bfo(b) << 16);
}
__device__ inline short8 cvt8(float4 a, float4 b){
  short8 r;
  r[0]=bfo(a.x); r[1]=bfo(a.y); r[2]=bfo(a.z); r[3]=bfo(a.w);
  r[4]=bfo(b.x); r[5]=bfo(b.y); r[6]=bfo(b.z); r[7]=bfo(b.w);
  return r;
}
__device__ inline float sigf(float v){ return 1.f/(1.f + __expf(-v)); }
__device__ inline float tanhf2(float v){
  float a = fabsf(v);
  float e = __expf(-2.f*a);
  float r = (1.f-e)/(1.f+e);
  return v < 0.f ? -r : r;
}
__device__ inline f32x16 MFMA(short8 a, short8 b, f32x16 c){
  return __builtin_amdgcn_mfma_f32_32x32x16_bf16(a, b, c, 0, 0, 0);
}
__device__ inline void stu(short* p, unsigned v){
  __hip_atomic_store((unsigned*)p, v, __ATOMIC_RELAXED, __HIP_MEMORY_SCOPE_AGENT);
}
__device__ inline void st8f(float* p, float a, float b){
  unsigned ua, ub; __builtin_memcpy(&ua, &a, 4); __builtin_memcpy(&ub, &b, 4);
  unsigned long long v = (unsigned long long)ua | ((unsigned long long)ub << 32);
  __hip_atomic_store((unsigned long long*)p, v, __ATOMIC_RELAXED, __HIP_MEMORY_SCOPE_AGENT);
}
__device__ inline unsigned pollld(const unsigned* p){
  return __hip_atomic_load(p, __ATOMIC_RELAXED, __HIP_MEMORY_SCOPE_AGENT);
}
__device__ inline short8 ldh8(const short* p){
  unsigned long long a = __hip_atomic_load((const unsigned long long*)p,
                          __ATOMIC_RELAXED, __HIP_MEMORY_SCOPE_AGENT);
  unsigned long long b = __hip_atomic_load((const unsigned long long*)(p+4),
                          __ATOMIC_RELAXED, __HIP_MEMORY_SCOPE_AGENT);
  short8 r;
  __builtin_memcpy(&r, &a, 8);
  __builtin_memcpy(((char*)&r)+8, &b, 8);
  return r;
}

// wait all 64 per-block flags of a domain >= e (ring-fallback path)
__device__ inline void waitflags_all(const unsigned* f, unsigned e, int lane){
  const unsigned* p = f + lane;
  for(;;){
    unsigned a = pollld(p);
    if (__all(a >= e)) break;
  }
  asm volatile("" ::: "memory");
}

// A-panel GEMM: K=256 eighth, 16 kg-pairs; window = 16 per-block flags in ONE
// 64B line; ballot-split 8+8 so chunk-1 MFMA hides chunk-2 stragglers.
__device__ inline void gemmA_wait(const short* __restrict__ slot,
                                  const unsigned* __restrict__ win, unsigned e,
                                  int lane, int kgbase,
                                  const short8 (&bf)[2][16], f32x16& a0, f32x16& a1)
{
  const int row = lane & 31, ksel = lane >> 5;
  const unsigned* fp = win + (lane & 15);
  const unsigned long long M1 = 0x00FF00FF00FF00FFULL;  // flags 0-7 (lane&15 < 8)
  const unsigned long long M2 = 0xFF00FF00FF00FF00ULL;  // flags 8-15
  unsigned long long bal;
  for(;;){
    unsigned f = pollld(fp);
    bal = __ballot(f >= e);
    if ((bal & M1) == M1) break;
  }
  asm volatile("" ::: "memory");
#pragma unroll
  for (int s = 0; s < 8; ++s){
    const short8 a = *(const short8*)(slot + ((size_t)(kgbase + s*2 + ksel)*32 + row)*8);
    a0 = MFMA(a, bf[0][s], a0);
    a1 = MFMA(a, bf[1][s], a1);
  }
  while ((bal & M2) != M2){
    unsigned f = pollld(fp);
    bal = __ballot(f >= e);
  }
  asm volatile("" ::: "memory");
#pragma unroll
  for (int s = 8; s < 16; ++s){
    const short8 a = *(const short8*)(slot + ((size_t)(kgbase + s*2 + ksel)*32 + row)*8);
    a0 = MFMA(a, bf[0][s], a0);
    a1 = MFMA(a, bf[1][s], a1);
  }
}
__device__ inline void gemmA_now(const short* __restrict__ slot, int lane, int kgbase,
                                 const short8 (&bf)[2][16], f32x16& a0, f32x16& a1)
{
  const int row = lane & 31, ksel = lane >> 5;
#pragma unroll
  for (int s = 0; s < 16; ++s){
    const short8 a = *(const short8*)(slot + ((size_t)(kgbase + s*2 + ksel)*32 + row)*8);
    a0 = MFMA(a, bf[0][s], a0);
    a1 = MFMA(a, bf[1][s], a1);
  }
}
__device__ inline void gemmA_bp(const short* __restrict__ slot, int lane, int kgbase,
                                const short8 (&bf)[2][16], f32x16& a0, f32x16& a1)
{
  const int row = lane & 31, ksel = lane >> 5;
#pragma unroll
  for (int s = 0; s < 16; ++s){
    const short8 a = ldh8(slot + ((size_t)(kgbase + s*2 + ksel)*32 + row)*8);
    a0 = MFMA(a, bf[0][s], a0);
    a1 = MFMA(a, bf[1][s], a1);
  }
}

// ---------------- prologue kernels ----------------

__global__ void lstm_prep(const float* __restrict__ bi, const float* __restrict__ bh,
                          float* __restrict__ bsum, unsigned* __restrict__ flags)
{
  int i = blockIdx.x*256 + threadIdx.x;
  if (i < 1024) flags[i] = 0;            // 4 domains x 64 block-flags
  if (i < 2*NG) bsum[i] = bi[i] + bh[i];
}

// W_i/W_h [2][1024][4096] f32 -> wT [2][4096][2048] bf16 (gate-col major, k inner)
__global__ void lstm_tr(const float* __restrict__ Wi, const float* __restrict__ Wh,
                        short* __restrict__ wT)
{
  __shared__ float tile[32][33];
  const int z = blockIdx.z, l = z >> 1, s = z & 1;
  const float* W = (s ? Wh : Wi) + (size_t)l*1024*4096;
  const int k0 = blockIdx.y*32, n0 = blockIdx.x*32;
  const int tx = threadIdx.x & 31, ty = threadIdx.x >> 5;
#pragma unroll
  for (int i = 0; i < 32; i += 8)
    tile[ty+i][tx] = W[(size_t)(k0+ty+i)*4096 + n0 + tx];
  __syncthreads();
#pragma unroll
  for (int i = 0; i < 32; i += 8)
    wT[((size_t)l*NG + n0+ty+i)*KTOT + s*1024 + k0 + tx] = bfo(tile[tx][ty+i]);
}

// x [64][512][1024] f32 -> xf [512][2 rh][128 kg][32 r][8] bf16
__global__ void lstm_xfrag(const float* __restrict__ x, short* __restrict__ xf)
{
  const int t = blockIdx.x;
  const int rh = blockIdx.y >> 4, kgb = blockIdx.y & 15;   // grid (512, 32)
  const int r = threadIdx.x >> 3, kq = threadIdx.x & 7;
  const int kg = kgb*8 + kq;
  const int grow = rh*32 + r;
  const float* p = x + ((size_t)grow*SEQ + t)*HID + kg*8;
  float4 a = *(const float4*)p, b = *(const float4*)(p + 4);
  *(short8*)(xf + ((size_t)t*2 + rh)*SLOT32 + ((size_t)kg*32 + r)*8) = cvt8(a, b);
}

// ---------------- main persistent kernel ----------------

__global__ void __launch_bounds__(512, 1)
lstm_main(const float* __restrict__ x,
          const float* __restrict__ h0in,
          const float* __restrict__ c0in,
          float* __restrict__ dout,
          const short* __restrict__ wT,
          const float* __restrict__ bsum,
          short* __restrict__ hseq0,
          short* __restrict__ h1seq,
          unsigned* __restrict__ flags,
          const short* __restrict__ xf,
          int use_xf, int use_seq1)
{
  const int blk  = blockIdx.x;          // 256 blocks
  const int l    = blk & 1;             // layer
  const int rh   = (blk >> 1) & 1;      // row half (rows rh*32..+32)
  const int lblk = blk >> 2;            // 0..63, owns dims [lblk*16,+16)
  const int dom  = blk & 3;             // sync domain = (rh,l)
  const int dom0 = 2*rh;                // layer-0 domain of same row half
  const int tid  = threadIdx.x;
  const int lane = tid & 63;
  const int w    = tid >> 6;            // K-eighth: w<4 = x-part, w>=4 = h-part
  const int c31  = lane & 31;

  __shared__ float planes[8][32][65];   // one plane per wave (no RMW, no B1)
  __shared__ float cst[32][17];
  __shared__ float bsm[64];

  __builtin_amdgcn_fence(__ATOMIC_ACQUIRE, "agent");   // once: drop stale lines

  unsigned* dfl  = flags + dom*64;      // per-BLOCK flags; window = 16 = 1 line
  unsigned* dfl0 = flags + dom0*64;
  unsigned* myflag = dfl + lblk;

  // ---- init ----
  if (tid < 64) bsm[tid] = bsum[l*NG + (tid>>4)*HID + lblk*DPB + (tid&15)];
  if (lane < 32){
    const int r = lane;
    const int grow = rh*32 + r;
    size_t o = ((size_t)l*B64 + grow)*HID + lblk*DPB + w*2;
    cst[r][w*2]   = c0in[o];
    cst[r][w*2+1] = c0in[o+1];
    const int kg = lblk*2 + (w>>2);
    short* hm1 = (l ? h1seq : hseq0) + (size_t)rh*SLOT32;   // slot 0 (both modes)
    stu(hm1 + ((size_t)kg*32 + r)*8 + ((w*2)&7), packbf2(h0in[o], h0in[o+1]));
  }
  // persistent B fragments: 64 cols x 256 k = 128 VGPRs
  short8 bf[2][16];
  {
    const short* wl = wT + (size_t)l*NG*KTOT;
#pragma unroll
    for (int cI = 0; cI < 2; ++cI){
      const int c  = cI*32 + c31;
      const int gc = (c>>4)*HID + lblk*DPB + (c&15);
      const short* wp = wl + (size_t)gc*KTOT + w*256 + (lane>>5)*8;
#pragma unroll
      for (int s = 0; s < 16; ++s)
        bf[cI][s] = *(const short8*)(wp + s*16);
    }
  }
  __syncthreads();    // drains vmcnt: init write-through stores in LLC
  if (tid == 0)
    __hip_atomic_store(myflag, 1u, __ATOMIC_RELAXED, __HIP_MEMORY_SCOPE_AGENT);

  float hf0 = 0.f, hf1 = 0.f;

  for (int t = 0; t < SEQ; ++t){
    f32x16 a0, a1;
#pragma unroll
    for (int i = 0; i < 16; ++i){ a0[i] = 0.f; a1[i] = 0.f; }

    if (w < 4){
      // ---- x-part ----
      if (l == 0){
        if (use_xf){
          gemmA_now(xf + ((size_t)t*2 + rh)*SLOT32, lane, w*32, bf, a0, a1);
        } else {
          const int row = lane & 31, ksel = lane >> 5;
          const int grow = rh*32 + row;
          const float* p = x + ((size_t)grow*SEQ + t)*HID;
#pragma unroll
          for (int s = 0; s < 16; ++s){
            const int kg = w*32 + s*2 + ksel;
            short8 a = cvt8(*(const float4*)(p + kg*8), *(const float4*)(p + kg*8 + 4));
            a0 = MFMA(a, bf[0][s], a0);
            a1 = MFMA(a, bf[1][s], a1);
          }
        }
      } else {
        // layer-1 input = h0(t): hseq0 slot t+1, window = 16 layer-0 blocks
        gemmA_wait(hseq0 + ((size_t)(t+1)*2 + rh)*SLOT32,
                   dfl0 + w*16, (unsigned)t + 2u,
                   lane, w*32, bf, a0, a1);
      }
    } else {
      // ---- h-part: own layer h(t-1) ----
      if (l == 0){
        gemmA_wait(hseq0 + ((size_t)t*2 + rh)*SLOT32,
                   dfl + (w-4)*16, (unsigned)t + 1u,
                   lane, (w-4)*32, bf, a0, a1);
      } else if (use_seq1){
        gemmA_wait(h1seq + ((size_t)t*2 + rh)*SLOT32,
                   dfl + (w-4)*16, (unsigned)t + 1u,
                   lane, (w-4)*32, bf, a0, a1);
      } else {
        // ring fallback: full-domain wait + bypass loads
        waitflags_all(dfl, (unsigned)t + 1u, lane);
        gemmA_bp(h1seq + ((size_t)(t&1)*2 + rh)*SLOT32, lane, (w-4)*32, bf, a0, a1);
      }
    }

    // ---- each wave writes its OWN plane (no RMW) ----
#pragma unroll
    for (int r = 0; r < 16; ++r){
      const int rr = (r&3) + 8*(r>>2) + 4*(lane>>5);
      planes[w][rr][c31]      = a0[r];
      planes[w][rr][32 + c31] = a1[r];
    }
    __syncthreads();   // B2: all planes written

    // ---- pointwise: wave w owns dims {2w, 2w+1} x 32 rows (lanes 0-31) ----
    if (lane < 32){
      const int r = lane;
      float hn[2];
#pragma unroll
      for (int e = 0; e < 2; ++e){
        const int d = w*2 + e;
        float gv[4];
#pragma unroll
        for (int g = 0; g < 4; ++g){
          float s = bsm[g*16 + d];
#pragma unroll
          for (int p = 0; p < 8; ++p)
            s += planes[p][r][g*16 + d];
          gv[g] = s;
        }
        float cp = cst[r][d];
        float cn = sigf(gv[1])*cp + sigf(gv[0])*tanhf2(gv[2]);
        float hv = sigf(gv[3])*tanhf2(cn);
        cst[r][d] = cn;
        hn[e] = hv;
      }
      hf0 = hn[0]; hf1 = hn[1];
      const int kg = lblk*2 + (w>>2);
      short* so;
      if (l == 0)           so = hseq0 + ((size_t)(t+1)*2 + rh)*SLOT32;
      else if (use_seq1)    so = h1seq + ((size_t)(t+1)*2 + rh)*SLOT32;
      else                  so = h1seq + ((size_t)((t+1)&1)*2 + rh)*SLOT32;
      stu(so + ((size_t)kg*32 + r)*8 + ((w*2)&7), packbf2(hn[0], hn[1]));
    }
    __syncthreads();   // B3: drains ALL waves' h-stores (vmcnt0 before barrier)
    if (tid == 0)
      __hip_atomic_store(myflag, (unsigned)t + 2u,
                         __ATOMIC_RELAXED, __HIP_MEMORY_SCOPE_AGENT);
    // deferred (off critical path): layer-1 output write
    if (l == 1 && lane < 32){
      const int grow = rh*32 + lane;
      st8f(dout + ((size_t)grow*SEQ + t)*HID + lblk*DPB + w*2, hf0, hf1);
    }
  }

  // ---- epilogue: h_n / c_n ----
  if (lane < 32){
    const int r = lane;
    const int grow = rh*32 + r;
    const size_t tb = (size_t)B64*SEQ*HID;
    size_t o = ((size_t)l*B64 + grow)*HID + lblk*DPB + w*2;
    st8f(dout + tb + o, hf0, hf1);
    st8f(dout + tb + (size_t)2*B64*HID + o, cst[r][w*2], cst[r][w*2+1]);
  }
}

// ---------------- host ----------------

extern "C" void kernel_launch(void* const* d_in, const int* in_sizes, int n_in,
                              void* d_out, int out_size, void* d_ws, size_t ws_size,
                              hipStream_t stream)
{
  const float* x  = (const float*)d_in[0];
  const float* Wi = (const float*)d_in[1];
  const float* bi = (const float*)d_in[2];
  const float* Wh = (const float*)d_in[3];
  const float* bh = (const float*)d_in[4];
  const float* h0 = (const float*)d_in[5];
  const float* c0 = (const float*)d_in[6];
  float* out = (float*)d_out;

  char* ws = (char*)d_ws;
  unsigned* flags = (unsigned*)ws;                     // 4 dom x 64 block-flags
  float*    bsum  = (float*)(ws + 16384);              // 32 KB
  short*    wT    = (short*)(ws + 131072);             // 32 MB

  const size_t wT_bytes  = (size_t)2*NG*KTOT*2;        // 33,554,432
  const size_t seq_bytes = (size_t)NSLOT*2*SLOT32*2;   // 513*2*32768*2 = 67.2 MB
  size_t off = 131072 + wT_bytes;

  short* hseq0 = (short*)(ws + off); off += seq_bytes; // required (~101 MB total)
  if (ws_size < off) return;

  int use_seq1 = 0;
  short* h1seq = (short*)(ws + off);
  if (ws_size >= off + seq_bytes){ use_seq1 = 1; off += seq_bytes; }
  else {
    if (ws_size < off + (size_t)2*2*SLOT32*2) return;  // 2-slot ring, 256 KB
    off += (size_t)2*2*SLOT32*2;
  }

  int use_xf = 0;
  short* xf = (short*)(ws + off);
  if (ws_size >= off + (size_t)SEQ*2*SLOT32*2) use_xf = 1;   // +67 MB

  lstm_prep<<<32, 256, 0, stream>>>(bi, bh, bsum, flags);
  lstm_tr<<<dim3(128, 32, 4), 256, 0, stream>>>(Wi, Wh, wT);
  if (use_xf) lstm_xfrag<<<dim3(SEQ, 32), 256, 0, stream>>>(x, xf);
  lstm_main<<<256, 512, 0, stream>>>(x, h0, c0, out, wT, bsum, hseq0, h1seq,
                                     flags, xf, use_xf, use_seq1);
}

// Round 8
// 3162.497 us; speedup vs baseline: 9.7732x; 1.0750x over previous
//
#include <hip/hip_runtime.h>
#include <hip/hip_bf16.h>

// LSTM B=64 L=512 H=1024 x2, persistent kernel v8.
// v8 vs v7 (protocol semantics unchanged):
//  - per-pointwise-wave flags (4/block, wave w owns dims 4w..4w+3): posted after
//    wave-local vmcnt(0); B3/8-wave skew off the flag path. Consumer window is
//    still ONE 64-lane load (16 blocks x 4 waves contiguous).
//  - pipelined 2-outstanding asm flag poll (sc0 sc1, vmcnt(1) alternation):
//    detect at ~RTT/2 granularity instead of >=RTT.
//  - pointwise full-precision divides -> v_rcp_f32 (bf16 tolerance >> rcp err).
//  - dual MFMA accumulator chains (8-deep instead of 16-deep dependency).

#define B64  64
#define SEQ  512
#define HID  1024
#define KTOT 2048
#define NG   4096
#define DPB  16
#define SLOT32 32768           // shorts per (t, rhalf) frag slot = 128kg*32r*8
#define NSLOT (SEQ+1)

typedef __attribute__((ext_vector_type(8)))  short short8;
typedef __attribute__((ext_vector_type(16))) float f32x16;

__device__ inline short bfo(float v){
  __hip_bfloat16 h = __float2bfloat16(v);
  short s; __builtin_memcpy(&s, &h, 2); return s;
}
__device__ inline unsigned packbf2(float a, float b){
  return (unsigned)(unsigned short)bfo(a) | ((unsigned)(unsigned short)bfo(b) << 16);
}
__device__ inline short8 cvt8(float4 a, float4 b){
  short8 r;
  r[0]=bfo(a.x); r[1]=bfo(a.y); r[2]=bfo(a.z); r[3]=bfo(a.w);
  r[4]=bfo(b.x); r[5]=bfo(b.y); r[6]=bfo(b.z); r[7]=bfo(b.w);
  return r;
}
__device__ inline float frcp(float x){ float r; asm("v_rcp_f32 %0, %1" : "=v"(r) : "v"(x)); return r; }
__device__ inline float sigf(float v){ return frcp(1.f + __expf(-v)); }
__device__ inline float tanhf2(float v){
  float a = fabsf(v);
  float e = __expf(-2.f*a);
  float r = (1.f - e) * frcp(1.f + e);
  return v < 0.f ? -r : r;
}
__device__ inline f32x16 MFMA(short8 a, short8 b, f32x16 c){
  return __builtin_amdgcn_mfma_f32_32x32x16_bf16(a, b, c, 0, 0, 0);
}
__device__ inline void stu(short* p, unsigned v){
  __hip_atomic_store((unsigned*)p, v, __ATOMIC_RELAXED, __HIP_MEMORY_SCOPE_AGENT);
}
__device__ inline void st8f(float* p, float a, float b){
  unsigned ua, ub; __builtin_memcpy(&ua, &a, 4); __builtin_memcpy(&ub, &b, 4);
  unsigned long long v = (unsigned long long)ua | ((unsigned long long)ub << 32);
  __hip_atomic_store((unsigned long long*)p, v, __ATOMIC_RELAXED, __HIP_MEMORY_SCOPE_AGENT);
}
__device__ inline unsigned pollld(const unsigned* p){
  return __hip_atomic_load(p, __ATOMIC_RELAXED, __HIP_MEMORY_SCOPE_AGENT);
}
__device__ inline short8 ldh8(const short* p){
  unsigned long long a = __hip_atomic_load((const unsigned long long*)p,
                          __ATOMIC_RELAXED, __HIP_MEMORY_SCOPE_AGENT);
  unsigned long long b = __hip_atomic_load((const unsigned long long*)(p+4),
                          __ATOMIC_RELAXED, __HIP_MEMORY_SCOPE_AGENT);
  short8 r;
  __builtin_memcpy(&r, &a, 8);
  __builtin_memcpy(((char*)&r)+8, &b, 8);
  return r;
}

// pipelined 2-outstanding poll: lane checks win[lane] >= e, all 64 lanes.
__device__ inline void wait_ge(const unsigned* win, unsigned e, int lane){
  const unsigned* fp = win + lane;
  unsigned f0, f1;
  asm volatile(
    "global_load_dword %[f0], %[ad], off sc0 sc1\n\t"
    "Lp%=:\n\t"
    "global_load_dword %[f1], %[ad], off sc0 sc1\n\t"
    "s_waitcnt vmcnt(1)\n\t"
    "v_cmp_ge_u32 vcc, %[f0], %[e]\n\t"
    "s_cmp_eq_u64 vcc, -1\n\t"
    "s_cbranch_scc1 Ld%=\n\t"
    "global_load_dword %[f0], %[ad], off sc0 sc1\n\t"
    "s_waitcnt vmcnt(1)\n\t"
    "v_cmp_ge_u32 vcc, %[f1], %[e]\n\t"
    "s_cmp_eq_u64 vcc, -1\n\t"
    "s_cbranch_scc0 Lp%=\n\t"
    "Ld%=:\n\t"
    "s_waitcnt vmcnt(0)\n\t"
    : [f0]"=&v"(f0), [f1]"=&v"(f1)
    : [ad]"v"(fp), [e]"v"(e)
    : "vcc", "scc", "memory");
}

// ring-fallback: all 256 per-wave flags of a domain >= e
__device__ inline void waitflags_all256(const unsigned* f, unsigned e, int lane){
  for(;;){
    unsigned m0 = pollld(f + lane),       m1 = pollld(f + 64 + lane);
    unsigned m2 = pollld(f + 128 + lane), m3 = pollld(f + 192 + lane);
    if (__all((m0>=e) && (m1>=e) && (m2>=e) && (m3>=e))) break;
  }
  asm volatile("" ::: "memory");
}

// A-panel GEMM: K=256 eighth, 16 kg-pairs, dual accumulator chains.
__device__ inline void gemmA_core(const short* __restrict__ slot, int lane, int kgbase,
                                  const short8 (&bf)[2][16], f32x16& A0, f32x16& A1)
{
  const int row = lane & 31, ksel = lane >> 5;
  f32x16 x0, x1, y0, y1;
#pragma unroll
  for (int i = 0; i < 16; ++i){ x0[i]=0.f; x1[i]=0.f; y0[i]=0.f; y1[i]=0.f; }
#pragma unroll
  for (int s = 0; s < 16; s += 2){
    const short8 a  = *(const short8*)(slot + ((size_t)(kgbase + s*2     + ksel)*32 + row)*8);
    const short8 a2 = *(const short8*)(slot + ((size_t)(kgbase + (s+1)*2 + ksel)*32 + row)*8);
    x0 = MFMA(a,  bf[0][s],   x0);
    x1 = MFMA(a,  bf[1][s],   x1);
    y0 = MFMA(a2, bf[0][s+1], y0);
    y1 = MFMA(a2, bf[1][s+1], y1);
  }
  A0 = x0 + y0;
  A1 = x1 + y1;
}
__device__ inline void gemmA_wait(const short* __restrict__ slot,
                                  const unsigned* __restrict__ win, unsigned e,
                                  int lane, int kgbase,
                                  const short8 (&bf)[2][16], f32x16& A0, f32x16& A1)
{
  wait_ge(win, e, lane);
  gemmA_core(slot, lane, kgbase, bf, A0, A1);
}
__device__ inline void gemmA_bp(const short* __restrict__ slot, int lane, int kgbase,
                                const short8 (&bf)[2][16], f32x16& A0, f32x16& A1)
{
  const int row = lane & 31, ksel = lane >> 5;
  f32x16 x0, x1;
#pragma unroll
  for (int i = 0; i < 16; ++i){ x0[i]=0.f; x1[i]=0.f; }
#pragma unroll
  for (int s = 0; s < 16; ++s){
    const short8 a = ldh8(slot + ((size_t)(kgbase + s*2 + ksel)*32 + row)*8);
    x0 = MFMA(a, bf[0][s], x0);
    x1 = MFMA(a, bf[1][s], x1);
  }
  A0 = x0; A1 = x1;
}

// ---------------- prologue kernels ----------------

__global__ void lstm_prep(const float* __restrict__ bi, const float* __restrict__ bh,
                          float* __restrict__ bsum, unsigned* __restrict__ flags)
{
  int i = blockIdx.x*256 + threadIdx.x;
  if (i < 1024) flags[i] = 0;            // 4 domains x 64 blk x 4 pw-waves
  if (i < 2*NG) bsum[i] = bi[i] + bh[i];
}

// W_i/W_h [2][1024][4096] f32 -> wT [2][4096][2048] bf16 (gate-col major, k inner)
__global__ void lstm_tr(const float* __restrict__ Wi, const float* __restrict__ Wh,
                        short* __restrict__ wT)
{
  __shared__ float tile[32][33];
  const int z = blockIdx.z, l = z >> 1, s = z & 1;
  const float* W = (s ? Wh : Wi) + (size_t)l*1024*4096;
  const int k0 = blockIdx.y*32, n0 = blockIdx.x*32;
  const int tx = threadIdx.x & 31, ty = threadIdx.x >> 5;
#pragma unroll
  for (int i = 0; i < 32; i += 8)
    tile[ty+i][tx] = W[(size_t)(k0+ty+i)*4096 + n0 + tx];
  __syncthreads();
#pragma unroll
  for (int i = 0; i < 32; i += 8)
    wT[((size_t)l*NG + n0+ty+i)*KTOT + s*1024 + k0 + tx] = bfo(tile[tx][ty+i]);
}

// x [64][512][1024] f32 -> xf [512][2 rh][128 kg][32 r][8] bf16
__global__ void lstm_xfrag(const float* __restrict__ x, short* __restrict__ xf)
{
  const int t = blockIdx.x;
  const int rh = blockIdx.y >> 4, kgb = blockIdx.y & 15;   // grid (512, 32)
  const int r = threadIdx.x >> 3, kq = threadIdx.x & 7;
  const int kg = kgb*8 + kq;
  const int grow = rh*32 + r;
  const float* p = x + ((size_t)grow*SEQ + t)*HID + kg*8;
  float4 a = *(const float4*)p, b = *(const float4*)(p + 4);
  *(short8*)(xf + ((size_t)t*2 + rh)*SLOT32 + ((size_t)kg*32 + r)*8) = cvt8(a, b);
}

// ---------------- main persistent kernel ----------------

__global__ void __launch_bounds__(512, 1)
lstm_main(const float* __restrict__ x,
          const float* __restrict__ h0in,
          const float* __restrict__ c0in,
          float* __restrict__ dout,
          const short* __restrict__ wT,
          const float* __restrict__ bsum,
          short* __restrict__ hseq0,
          short* __restrict__ h1seq,
          unsigned* __restrict__ flags,
          const short* __restrict__ xf,
          int use_xf, int use_seq1)
{
  const int blk  = blockIdx.x;          // 256 blocks
  const int l    = blk & 1;             // layer
  const int rh   = (blk >> 1) & 1;      // row half (rows rh*32..+32)
  const int lblk = blk >> 2;            // 0..63, owns dims [lblk*16,+16)
  const int dom  = blk & 3;             // sync domain = (rh,l)
  const int dom0 = 2*rh;                // layer-0 domain of same row half
  const int tid  = threadIdx.x;
  const int lane = tid & 63;
  const int w    = tid >> 6;            // K-eighth: w<4 = x-part, w>=4 = h-part
  const int c31  = lane & 31;

  __shared__ float planes[8][32][65];   // one plane per wave
  __shared__ float cst[32][17];
  __shared__ float bsm[64];

  __builtin_amdgcn_fence(__ATOMIC_ACQUIRE, "agent");   // once: drop stale lines

  unsigned* dfl  = flags + dom*256;     // [64 blk][4 pw-wave] flags
  unsigned* dfl0 = flags + dom0*256;

  // pointwise mapping (waves 0-3): row = lane&31, dim pair dp = w*2 + (lane>>5)
  const int prow = lane & 31;
  const int pd0  = (w*2 + (lane>>5)) * 2;    // first of 2 dims (valid for w<4)

  // ---- init ----
  if (tid < 64) bsm[tid] = bsum[l*NG + (tid>>4)*HID + lblk*DPB + (tid&15)];
  if (w < 4){
    size_t o = ((size_t)l*B64 + rh*32 + prow)*HID + lblk*DPB + pd0;
    cst[prow][pd0]   = c0in[o];
    cst[prow][pd0+1] = c0in[o+1];
    const int kg = lblk*2 + (pd0>>3);
    short* hm1 = (l ? h1seq : hseq0) + (size_t)rh*SLOT32;   // slot 0 (both modes)
    stu(hm1 + ((size_t)kg*32 + prow)*8 + (pd0&7), packbf2(h0in[o], h0in[o+1]));
  }
  // persistent B fragments: 64 cols x 256 k = 128 VGPRs
  short8 bf[2][16];
  {
    const short* wl = wT + (size_t)l*NG*KTOT;
#pragma unroll
    for (int cI = 0; cI < 2; ++cI){
      const int c  = cI*32 + c31;
      const int gc = (c>>4)*HID + lblk*DPB + (c&15);
      const short* wp = wl + (size_t)gc*KTOT + w*256 + (lane>>5)*8;
#pragma unroll
      for (int s = 0; s < 16; ++s)
        bf[cI][s] = *(const short8*)(wp + s*16);
    }
  }
  __syncthreads();    // drains vmcnt: init write-through stores in LLC
  if (w < 4 && lane == 0)
    __hip_atomic_store(dfl + lblk*4 + w, 1u, __ATOMIC_RELAXED, __HIP_MEMORY_SCOPE_AGENT);

  float hf0 = 0.f, hf1 = 0.f;

  for (int t = 0; t < SEQ; ++t){
    f32x16 a0, a1;

    if (w < 4){
      // ---- x-part ----
      if (l == 0){
        if (use_xf){
          gemmA_core(xf + ((size_t)t*2 + rh)*SLOT32, lane, w*32, bf, a0, a1);
        } else {
          const int row = lane & 31, ksel = lane >> 5;
          const float* p = x + ((size_t)(rh*32 + row)*SEQ + t)*HID;
          f32x16 x0, x1;
#pragma unroll
          for (int i = 0; i < 16; ++i){ x0[i]=0.f; x1[i]=0.f; }
#pragma unroll
          for (int s = 0; s < 16; ++s){
            const int kg = w*32 + s*2 + ksel;
            short8 a = cvt8(*(const float4*)(p + kg*8), *(const float4*)(p + kg*8 + 4));
            x0 = MFMA(a, bf[0][s], x0);
            x1 = MFMA(a, bf[1][s], x1);
          }
          a0 = x0; a1 = x1;
        }
      } else {
        // layer-1 input = h0(t): hseq0 slot t+1; window = 16 l0 blocks x 4 waves
        gemmA_wait(hseq0 + ((size_t)(t+1)*2 + rh)*SLOT32,
                   dfl0 + w*64, (unsigned)t + 2u,
                   lane, w*32, bf, a0, a1);
      }
    } else {
      // ---- h-part: own layer h(t-1) ----
      if (l == 0){
        gemmA_wait(hseq0 + ((size_t)t*2 + rh)*SLOT32,
                   dfl + (w-4)*64, (unsigned)t + 1u,
                   lane, (w-4)*32, bf, a0, a1);
      } else if (use_seq1){
        gemmA_wait(h1seq + ((size_t)t*2 + rh)*SLOT32,
                   dfl + (w-4)*64, (unsigned)t + 1u,
                   lane, (w-4)*32, bf, a0, a1);
      } else {
        waitflags_all256(dfl, (unsigned)t + 1u, lane);
        gemmA_bp(h1seq + ((size_t)(t&1)*2 + rh)*SLOT32, lane, (w-4)*32, bf, a0, a1);
      }
    }

    // ---- each wave writes its OWN plane ----
#pragma unroll
    for (int r = 0; r < 16; ++r){
      const int rr = (r&3) + 8*(r>>2) + 4*(lane>>5);
      planes[w][rr][c31]      = a0[r];
      planes[w][rr][32 + c31] = a1[r];
    }
    __syncthreads();   // B2: all planes written

    // ---- pointwise (waves 0-3, all 64 lanes; 2 dims x 1 row each) ----
    if (w < 4){
      float hn[2];
#pragma unroll
      for (int e = 0; e < 2; ++e){
        const int d = pd0 + e;
        float gv[4];
#pragma unroll
        for (int g = 0; g < 4; ++g){
          float s = bsm[g*16 + d];
#pragma unroll
          for (int p = 0; p < 8; ++p)
            s += planes[p][prow][g*16 + d];
          gv[g] = s;
        }
        float cp = cst[prow][d];
        float cn = sigf(gv[1])*cp + sigf(gv[0])*tanhf2(gv[2]);
        float hv = sigf(gv[3])*tanhf2(cn);
        cst[prow][d] = cn;
        hn[e] = hv;
      }
      hf0 = hn[0]; hf1 = hn[1];
      const int kg = lblk*2 + (pd0>>3);
      short* so;
      if (l == 0)           so = hseq0 + ((size_t)(t+1)*2 + rh)*SLOT32;
      else if (use_seq1)    so = h1seq + ((size_t)(t+1)*2 + rh)*SLOT32;
      else                  so = h1seq + ((size_t)((t+1)&1)*2 + rh)*SLOT32;
      stu(so + ((size_t)kg*32 + prow)*8 + (pd0&7), packbf2(hn[0], hn[1]));
      asm volatile("s_waitcnt vmcnt(0)" ::: "memory");   // wave-local store ack
      if (lane == 0)
        __hip_atomic_store(dfl + lblk*4 + w, (unsigned)t + 2u,
                           __ATOMIC_RELAXED, __HIP_MEMORY_SCOPE_AGENT);
      // off critical path: layer-1 output write
      if (l == 1)
        st8f(dout + ((size_t)(rh*32 + prow)*SEQ + t)*HID + lblk*DPB + pd0, hn[0], hn[1]);
    }
    __syncthreads();   // B3: planes/cst reusable next step
  }

  // ---- epilogue: h_n / c_n ----
  if (w < 4){
    const int grow = rh*32 + prow;
    const size_t tb = (size_t)B64*SEQ*HID;
    size_t o = ((size_t)l*B64 + grow)*HID + lblk*DPB + pd0;
    st8f(dout + tb + o, hf0, hf1);
    st8f(dout + tb + (size_t)2*B64*HID + o, cst[prow][pd0], cst[prow][pd0+1]);
  }
}

// ---------------- host ----------------

extern "C" void kernel_launch(void* const* d_in, const int* in_sizes, int n_in,
                              void* d_out, int out_size, void* d_ws, size_t ws_size,
                              hipStream_t stream)
{
  const float* x  = (const float*)d_in[0];
  const float* Wi = (const float*)d_in[1];
  const float* bi = (const float*)d_in[2];
  const float* Wh = (const float*)d_in[3];
  const float* bh = (const float*)d_in[4];
  const float* h0 = (const float*)d_in[5];
  const float* c0 = (const float*)d_in[6];
  float* out = (float*)d_out;

  char* ws = (char*)d_ws;
  unsigned* flags = (unsigned*)ws;                     // 4 dom x 64 blk x 4 w
  float*    bsum  = (float*)(ws + 16384);              // 32 KB
  short*    wT    = (short*)(ws + 131072);             // 32 MB

  const size_t wT_bytes  = (size_t)2*NG*KTOT*2;        // 33,554,432
  const size_t seq_bytes = (size_t)NSLOT*2*SLOT32*2;   // 67.2 MB
  size_t off = 131072 + wT_bytes;

  short* hseq0 = (short*)(ws + off); off += seq_bytes; // required
  if (ws_size < off) return;

  int use_seq1 = 0;
  short* h1seq = (short*)(ws + off);
  if (ws_size >= off + seq_bytes){ use_seq1 = 1; off += seq_bytes; }
  else {
    if (ws_size < off + (size_t)2*2*SLOT32*2) return;  // 2-slot ring, 256 KB
    off += (size_t)2*2*SLOT32*2;
  }

  int use_xf = 0;
  short* xf = (short*)(ws + off);
  if (ws_size >= off + (size_t)SEQ*2*SLOT32*2) use_xf = 1;   // +67 MB

  lstm_prep<<<32, 256, 0, stream>>>(bi, bh, bsum, flags);
  lstm_tr<<<dim3(128, 32, 4), 256, 0, stream>>>(Wi, Wh, wT);
  if (use_xf) lstm_xfrag<<<dim3(SEQ, 32), 256, 0, stream>>>(x, xf);
  lstm_main<<<256, 512, 0, stream>>>(x, h0, c0, out, wT, bsum, hseq0, h1seq,
                                     flags, xf, use_xf, use_seq1);
}